// Round 11
// baseline (1013.183 us; speedup 1.0000x reference)
//
#include <hip/hip_runtime.h>

#define NB 32
#define NS 48
#define NL 48
#define NH 1024
#define NE 1024
#define NV 32000
#define NR (NS*NB)      // 1536
#define K3H 3072
#define RA_BLOCKS 64
#define RB_BLOCKS 128
#define RC_BLOCKS 64
#define NBLK_FULL (RA_BLOCKS + RB_BLOCKS + RC_BLOCKS)   // 256

typedef unsigned short u16;
typedef __bf16 bf16x8 __attribute__((ext_vector_type(8)));
typedef unsigned short ushort8 __attribute__((ext_vector_type(8)));
typedef float f32x4 __attribute__((ext_vector_type(4)));
typedef unsigned int uint4v __attribute__((ext_vector_type(4)));

__device__ __forceinline__ float bf2f(u16 x) {
    union { unsigned u; float f; } c; c.u = ((unsigned)x) << 16; return c.f;
}
__device__ __forceinline__ u16 f2bf(float f) {
    union { float f; unsigned u; } c; c.f = f;
    unsigned r = (c.u + 0x7FFFu + ((c.u >> 16) & 1u)) >> 16;
    return (u16)r;
}
__device__ __forceinline__ f32x4 mfma16(bf16x8 a, bf16x8 b, f32x4 c) {
    return __builtin_amdgcn_mfma_f32_16x16x32_bf16(a, b, c, 0, 0, 0);
}
__device__ __forceinline__ void gld_lds16(const void* g, void* l) {
    __builtin_amdgcn_global_load_lds((const __attribute__((address_space(1))) void*)g,
                                     (__attribute__((address_space(3))) void*)l, 16, 0, 0);
}

// ---- coherent store (write-through, bypass L1/L2), 16B ----
__device__ __forceinline__ void st16_coh(void* p, uint4v v) {
    asm volatile("global_store_dwordx4 %0, %1, off sc0 sc1" :: "v"(p), "v"(v) : "memory");
}
// ---- single-line waiter poll (coherent load) ----
__device__ __forceinline__ void waitb(const int* line, int tgt) {
    if (tgt <= 0) return;
    int guard = 0; int v;
    for (;;) {
        asm volatile("global_load_dword %0, %1, off sc0 sc1\n\ts_waitcnt vmcnt(0)"
                     : "=v"(v) : "v"(line) : "memory");
        if (v >= tgt) return;
        __builtin_amdgcn_s_sleep(1);
        if (++guard > (1 << 20)) return;   // safety valve: wrong answer, not hang
    }
}
// ---- R5-proven producer arrive: cnt line -> super -> broadcast step to 24 lines ----
__device__ __forceinline__ void arrive2(int* cnt, int* superc, int* bcast, int lineMask, int val) {
    asm volatile("s_waitcnt vmcnt(0)" ::: "memory");
    int prev = __hip_atomic_fetch_add(cnt, 1, __ATOMIC_RELAXED, __HIP_MEMORY_SCOPE_AGENT);
    if ((prev & lineMask) == lineMask) {
        int p2 = __hip_atomic_fetch_add(superc, 1, __ATOMIC_RELAXED, __HIP_MEMORY_SCOPE_AGENT);
        if ((p2 & 7) == 7) {
#pragma unroll
            for (int i = 0; i < 24; ++i)
                asm volatile("global_store_dword %0, %1, off sc0 sc1"
                             :: "v"(bcast + i * 64), "v"(val) : "memory");
        }
    }
}

// ---------------- transpose + cast (fallback) ----------------
__global__ __launch_bounds__(256) void transpose_cast(const float* __restrict__ src, int K, int N,
                                                      char* __restrict__ dst, int bf16out) {
    __shared__ float tile[32][33];
    int k0 = blockIdx.y * 32, n0 = blockIdx.x * 32;
    int tx = threadIdx.x & 31, ty = threadIdx.x >> 5;
    for (int i = 0; i < 4; ++i) {
        int n = n0 + tx;
        float v = (n < N) ? src[(size_t)(k0 + ty + i*8) * N + n] : 0.f;
        tile[ty + i*8][tx] = v;
    }
    __syncthreads();
    for (int i = 0; i < 4; ++i) {
        int n = n0 + ty + i*8;
        int k = k0 + tx;
        if (n < N) {
            float v = tile[tx][ty + i*8];
            if (bf16out) ((u16*)dst)[(size_t)n * K + k] = f2bf(v);
            else         ((float*)dst)[(size_t)n * K + k] = v;
        }
    }
}

// ---------------- merged prologue: prep (blocks 0..3103) + weight transposes ----------------
__global__ __launch_bounds__(256) void prologue_all(
    const int* __restrict__ label, const float* __restrict__ emb,
    const float* __restrict__ enc, const float* __restrict__ inith,
    u16* __restrict__ xe, u16* __restrict__ encb, u16* __restrict__ hallx,
    const float* __restrict__ Whh_, const float* __restrict__ Wih_,
    const float* __restrict__ combW_, const float* __restrict__ attnW_,
    u16* __restrict__ whht, u16* __restrict__ wiht,
    u16* __restrict__ cw1t, u16* __restrict__ cw2t,
    u16* __restrict__ aw2t, u16* __restrict__ aw1t)
{
    int bid = blockIdx.x, t = threadIdx.x;
    if (bid < 3104) {
        int blk = bid;
        if (blk < NR) {
            int s = blk >> 5, b = blk & 31;
            int lab = label[b * NS + s];
            const float* src = emb + (size_t)lab * NE;
            u16* dst = xe + (size_t)blk * NE;
            for (int i = t; i < NE; i += 256) { float v = src[i]; dst[i] = f2bf(v > 0.f ? v : 0.f); }
        } else if (blk < 2 * NR) {
            int r = blk - NR;
            const float* src = enc + (size_t)r * NH;
            u16* dst = encb + (size_t)r * NH;
            for (int i = t; i < NH; i += 256) dst[i] = f2bf(src[i]);
        } else {
            int b = blk - 2 * NR;
            const float* src = inith + (size_t)b * NH;
            u16* dst = hallx + (size_t)b * NH;
            for (int i = t; i < NH; i += 256) dst[i] = f2bf(src[i]);
        }
        return;
    }
    __shared__ float tile[32][33];
    int tb = bid - 3104;
    const float* src; u16* dst; int N, local;
    if (tb < 3072)      { src = Whh_;  dst = whht; N = 3072; local = tb; }
    else if (tb < 6144) { src = Wih_;  dst = wiht; N = 3072; local = tb - 3072; }
    else if (tb < 7168) { src = combW_; dst = cw1t; N = 1024; local = tb - 6144; }
    else if (tb < 8192) { src = combW_ + (size_t)NH * NH; dst = cw2t; N = 1024; local = tb - 7168; }
    else if (tb < 8256) { src = attnW_ + (size_t)NH * NL; dst = aw2t; N = 48; local = tb - 8192; }
    else                { src = attnW_; dst = aw1t; N = 48; local = tb - 8256; }
    int tiles_x = (N + 31) >> 5;
    int n0 = (local % tiles_x) * 32, k0 = (local / tiles_x) * 32;
    int tx = t & 31, ty = t >> 5;
    for (int i = 0; i < 4; ++i) {
        int n = n0 + tx;
        float v = (n < N) ? src[(size_t)(k0 + ty + i*8) * N + n] : 0.f;
        tile[ty + i*8][tx] = v;
    }
    __syncthreads();
    for (int i = 0; i < 4; ++i) {
        int n = n0 + ty + i*8;
        int k = k0 + tx;
        if (n < N) dst[(size_t)n * 1024 + k] = f2bf(tile[tx][ty + i*8]);
    }
}

// ---------------- simxe ----------------
__global__ __launch_bounds__(384) void simxe2_kernel(const u16* __restrict__ xe, const u16* __restrict__ aw1t,
                                                     const float* __restrict__ attnB, float* __restrict__ simxe) {
    int r = blockIdx.x, t = threadIdx.x;
    int l = t >> 3, part = t & 7;
    const u16* x = xe + (size_t)r * 1024 + part * 128;
    const u16* ww = aw1t + (size_t)l * 1024 + part * 128;
    float acc = 0.f;
#pragma unroll
    for (int k = 0; k < 128; k += 8) {
        ushort8 xv = *reinterpret_cast<const ushort8*>(x + k);
        ushort8 wv = *reinterpret_cast<const ushort8*>(ww + k);
#pragma unroll
        for (int u = 0; u < 8; ++u) acc += bf2f(xv[u]) * bf2f(wv[u]);
    }
    acc += __shfl_xor(acc, 1);
    acc += __shfl_xor(acc, 2);
    acc += __shfl_xor(acc, 4);
    if (part == 0) simxe[(size_t)r * NL + l] = acc + attnB[l];
}

// ---------------- standalone bf16 MFMA GEMM (fallback) ----------------
template<int MODE>
__global__ __launch_bounds__(256) void gemm_bf16(const u16* __restrict__ A, const u16* __restrict__ Bt,
                                                 void* __restrict__ Cout, const float* __restrict__ bias, int N) {
    __shared__ u16 ldsA[128 * 64];
    __shared__ u16 ldsB[128 * 64];
    const int t = threadIdx.x;
    const int lane = t & 63, w = t >> 6;
    const int wm = w >> 1, wn = w & 1;
    const int m0 = blockIdx.x * 128, n0 = blockIdx.y * 128;
    f32x4 acc[4][4] = {};
    for (int kt = 0; kt < 16; ++kt) {
        const int k0 = kt * 64;
#pragma unroll
        for (int i = 0; i < 4; ++i) {
            int chunk = i * 256 + t;
            int row = chunk >> 3, slot = chunk & 7;
            int srck = ((slot ^ (row & 7)) * 8);
            gld_lds16(A  + (size_t)(m0 + row) * 1024 + k0 + srck, ldsA + (size_t)(i * 256 + w * 64) * 8);
            gld_lds16(Bt + (size_t)(n0 + row) * 1024 + k0 + srck, ldsB + (size_t)(i * 256 + w * 64) * 8);
        }
        asm volatile("s_waitcnt vmcnt(0)" ::: "memory");
        __syncthreads();
#pragma unroll
        for (int kk = 0; kk < 2; ++kk) {
            bf16x8 a[4], b[4];
#pragma unroll
            for (int f = 0; f < 4; ++f) {
                int rowA = wm * 64 + f * 16 + (lane & 15);
                int slotA = (kk * 4 + (lane >> 4)) ^ (rowA & 7);
                a[f] = *reinterpret_cast<const bf16x8*>(ldsA + rowA * 64 + slotA * 8);
                int rowB = wn * 64 + f * 16 + (lane & 15);
                int slotB = (kk * 4 + (lane >> 4)) ^ (rowB & 7);
                b[f] = *reinterpret_cast<const bf16x8*>(ldsB + rowB * 64 + slotB * 8);
            }
#pragma unroll
            for (int fm = 0; fm < 4; ++fm)
#pragma unroll
                for (int fn = 0; fn < 4; ++fn)
                    acc[fm][fn] = mfma16(a[fm], b[fn], acc[fm][fn]);
        }
        __syncthreads();
    }
#pragma unroll
    for (int fm = 0; fm < 4; ++fm) {
#pragma unroll
        for (int fn = 0; fn < 4; ++fn) {
#pragma unroll
            for (int rr = 0; rr < 4; ++rr) {
                int m = m0 + wm * 64 + fm * 16 + (lane >> 4) * 4 + rr;
                int n = n0 + wn * 64 + fn * 16 + (lane & 15);
                float v = acc[fm][fn][rr];
                if (bias) v += bias[n];
                if (MODE == 0)      ((float*)Cout)[(size_t)m * N + n] = v;
                else if (MODE == 2) ((u16*)Cout)[(size_t)m * N + n] = f2bf(v);
                else if (MODE == 1)
                    ((float*)Cout)[((size_t)(m & 31) * NS + (m >> 5)) * NV + n] = v;
                else
                    ((u16*)Cout)[((size_t)(m & 31) * NS + (m >> 5)) * NV + n] = f2bf(v);
            }
        }
    }
}

// ---------------- merged prologue GEMMs ----------------
__global__ __launch_bounds__(256) void gemm_pro(const u16* __restrict__ xe, const u16* __restrict__ cw2t,
                                                const u16* __restrict__ encb, const u16* __restrict__ cw1t,
                                                u16* __restrict__ gxe, u16* __restrict__ Pb,
                                                const float* __restrict__ combB) {
    __shared__ u16 ldsA[128 * 64];
    __shared__ u16 ldsB[128 * 64];
    const u16 *A, *Bt; u16* C; const float* bias;
    if (blockIdx.z == 0) { A = xe;   Bt = cw2t; C = gxe; bias = combB; }
    else                 { A = encb; Bt = cw1t; C = Pb;  bias = nullptr; }
    const int t = threadIdx.x;
    const int lane = t & 63, w = t >> 6;
    const int wm = w >> 1, wn = w & 1;
    const int m0 = blockIdx.x * 128, n0 = blockIdx.y * 128;
    f32x4 acc[4][4] = {};
    for (int kt = 0; kt < 16; ++kt) {
        const int k0 = kt * 64;
#pragma unroll
        for (int i = 0; i < 4; ++i) {
            int chunk = i * 256 + t;
            int row = chunk >> 3, slot = chunk & 7;
            int srck = ((slot ^ (row & 7)) * 8);
            gld_lds16(A  + (size_t)(m0 + row) * 1024 + k0 + srck, ldsA + (size_t)(i * 256 + w * 64) * 8);
            gld_lds16(Bt + (size_t)(n0 + row) * 1024 + k0 + srck, ldsB + (size_t)(i * 256 + w * 64) * 8);
        }
        asm volatile("s_waitcnt vmcnt(0)" ::: "memory");
        __syncthreads();
#pragma unroll
        for (int kk = 0; kk < 2; ++kk) {
            bf16x8 a[4], b[4];
#pragma unroll
            for (int f = 0; f < 4; ++f) {
                int rowA = wm * 64 + f * 16 + (lane & 15);
                int slotA = (kk * 4 + (lane >> 4)) ^ (rowA & 7);
                a[f] = *reinterpret_cast<const bf16x8*>(ldsA + rowA * 64 + slotA * 8);
                int rowB = wn * 64 + f * 16 + (lane & 15);
                int slotB = (kk * 4 + (lane >> 4)) ^ (rowB & 7);
                b[f] = *reinterpret_cast<const bf16x8*>(ldsB + rowB * 64 + slotB * 8);
            }
#pragma unroll
            for (int fm = 0; fm < 4; ++fm)
#pragma unroll
                for (int fn = 0; fn < 4; ++fn)
                    acc[fm][fn] = mfma16(a[fm], b[fn], acc[fm][fn]);
        }
        __syncthreads();
    }
#pragma unroll
    for (int fm = 0; fm < 4; ++fm) {
#pragma unroll
        for (int fn = 0; fn < 4; ++fn) {
#pragma unroll
            for (int rr = 0; rr < 4; ++rr) {
                int m = m0 + wm * 64 + fm * 16 + (lane >> 4) * 4 + rr;
                int n = n0 + wn * 64 + fn * 16 + (lane & 15);
                float v = acc[fm][fn][rr];
                if (bias) v += bias[n];
                C[(size_t)m * NH + n] = f2bf(v);
            }
        }
    }
}

// ---------------- 256x256 out-GEMM tile, double-buffered, coherent staged epilogue ----------
__device__ __forceinline__ void do_tile(char* smem, const u16* Ab, const u16* outWT,
                                        const float* outB, u16* logit,
                                        int mt, int nt, int t) {
    u16* A0 = (u16*)smem;             u16* B0 = (u16*)(smem + 32768);
    u16* A1 = (u16*)(smem + 65536);   u16* B1 = (u16*)(smem + 98304);
    const int w = t >> 6, lane = t & 63;
    const int r16 = lane & 15, kg = lane >> 4;
    const int wm = w >> 1, wn = w & 1;
    const int m0 = mt * 256, n0 = nt * 256;
    f32x4 acc[4][8] = {};

    auto issue = [&](int kt, u16* la, u16* lb) {
        const int k0 = kt * 64;
#pragma unroll
        for (int i = 0; i < 4; ++i) {
            int chunk = i * 512 + t;
            int row = chunk >> 3, slot = chunk & 7;
            int srck = ((slot ^ (row & 7)) * 8);
            gld_lds16(Ab + (size_t)(m0 + row) * 1024 + k0 + srck,
                      la + (size_t)(i * 512 + w * 64) * 8);
            gld_lds16(outWT + (size_t)(n0 + row) * 1024 + k0 + srck,
                      lb + (size_t)(i * 512 + w * 64) * 8);
        }
    };
    auto compute = [&](const u16* LA, const u16* LB) {
#pragma unroll
        for (int kk = 0; kk < 2; ++kk) {
            bf16x8 a[4], b[8];
#pragma unroll
            for (int f = 0; f < 4; ++f) {
                int rowA = wm * 64 + f * 16 + r16;
                int slotA = (kk * 4 + kg) ^ (rowA & 7);
                a[f] = *reinterpret_cast<const bf16x8*>(LA + rowA * 64 + slotA * 8);
            }
#pragma unroll
            for (int f = 0; f < 8; ++f) {
                int rowB = wn * 128 + f * 16 + r16;
                int slotB = (kk * 4 + kg) ^ (rowB & 7);
                b[f] = *reinterpret_cast<const bf16x8*>(LB + rowB * 64 + slotB * 8);
            }
#pragma unroll
            for (int fm = 0; fm < 4; ++fm)
#pragma unroll
                for (int fn = 0; fn < 8; ++fn)
                    acc[fm][fn] = mfma16(a[fm], b[fn], acc[fm][fn]);
        }
    };

    issue(0, A0, B0);
    for (int kt = 0; kt < 16; kt += 2) {
        issue(kt + 1, A1, B1);
        asm volatile("s_waitcnt vmcnt(8)" ::: "memory");
        __builtin_amdgcn_s_barrier();
        compute(A0, B0);
        __builtin_amdgcn_s_barrier();
        if (kt + 2 < 16) {
            issue(kt + 2, A0, B0);
            asm volatile("s_waitcnt vmcnt(8)" ::: "memory");
        } else {
            asm volatile("s_waitcnt vmcnt(0)" ::: "memory");
        }
        __builtin_amdgcn_s_barrier();
        compute(A1, B1);
        __builtin_amdgcn_s_barrier();
    }
    // stage tile in LDS, then coherent 16B row writes (cross-XCD visible)
    u16* stg = (u16*)smem;   // [256][264]
#pragma unroll
    for (int fm = 0; fm < 4; ++fm)
#pragma unroll
        for (int fn = 0; fn < 8; ++fn)
#pragma unroll
            for (int rr = 0; rr < 4; ++rr) {
                int mr = wm * 64 + fm * 16 + kg * 4 + rr;
                int nc = wn * 128 + fn * 16 + r16;
                stg[mr * 264 + nc] = f2bf(acc[fm][fn][rr] + outB[n0 + nc]);
            }
    __syncthreads();
    {
        int mr = t >> 1, cb = (t & 1) * 128;
        int m = m0 + mr;
        int orow = (m & 31) * NS + (m >> 5);
        u16* dst = logit + (size_t)orow * NV + n0 + cb;
        const u16* srcr = stg + mr * 264 + cb;
#pragma unroll
        for (int i = 0; i < 16; ++i) {
            uint4v v = *reinterpret_cast<const uint4v*>(srcr + i * 8);
            st16_coh(dst + i * 8, v);
        }
    }
    asm volatile("s_waitcnt vmcnt(0)" ::: "memory");
    __syncthreads();
}

// ---------------- fused log_softmax of one output row (512 threads) ----------------
__device__ __forceinline__ void softmax_row(char* smem, const u16* logit, float* dout, int m, int t) {
    u16* rowb = (u16*)smem;                 // 64000 B
    float* red = (float*)(smem + 64000);    // 16 f32
    const int orow = (m & 31) * NS + (m >> 5);
    const u16* src = logit + (size_t)orow * NV;
    float* dst = dout + (size_t)orow * NV;
    for (int i = t; i < NV / 8; i += 512)
        ((ushort8*)rowb)[i] = ((const ushort8*)src)[i];
    __syncthreads();
    float mx = -1e30f;
    for (int i = t; i < NV; i += 512) mx = fmaxf(mx, bf2f(rowb[i]));
    for (int o = 32; o >= 1; o >>= 1) mx = fmaxf(mx, __shfl_xor(mx, o));
    if ((t & 63) == 0) red[t >> 6] = mx;
    __syncthreads();
    mx = red[0];
#pragma unroll
    for (int i = 1; i < 8; ++i) mx = fmaxf(mx, red[i]);
    float sum = 0.f;
    for (int i = t; i < NV; i += 512) sum += __expf(bf2f(rowb[i]) - mx);
    for (int o = 32; o >= 1; o >>= 1) sum += __shfl_xor(sum, o);
    if ((t & 63) == 0) red[8 + (t >> 6)] = sum;
    __syncthreads();
    sum = 0.f;
#pragma unroll
    for (int i = 0; i < 8; ++i) sum += red[8 + i];
    float lse = mx + __logf(sum);
    for (int i = t; i < NV; i += 512) dst[i] = bf2f(rowb[i]) - lse;
    __syncthreads();
}

// queue-driven GEMM tail over group mt=5 (125 n-tiles), bumping gd5 per tile
__device__ __forceinline__ void queue_gemm(char* smem, int* qslot, int* qcnt, int* gd5,
                                           const u16* Ab, const u16* outWT,
                                           const float* outB, u16* logit, int t) {
    for (;;) {
        __syncthreads();
        if (t == 0) *qslot = __hip_atomic_fetch_add(qcnt, 1, __ATOMIC_RELAXED, __HIP_MEMORY_SCOPE_AGENT);
        __syncthreads();
        int nt = *qslot;
        if (nt >= 125) return;
        do_tile(smem, Ab, outWT, outB, logit, 5, nt, t);
        if (t == 0) __hip_atomic_fetch_add(gd5, 1, __ATOMIC_RELAXED, __HIP_MEMORY_SCOPE_AGENT);
    }
}

// drain all softmax row queues (gd[g] gates readiness)
__device__ __forceinline__ void drain_softmax(char* smem, int* qslot, int* gd, int* rowq,
                                              const u16* logit, float* dout, int t) {
    for (int g = 0; g < 6; ++g) {
        if (t == 0) waitb(gd + g * 64, 125);
        __syncthreads();
        for (;;) {
            __syncthreads();
            if (t == 0) *qslot = __hip_atomic_fetch_add(rowq + g * 64, 1, __ATOMIC_RELAXED, __HIP_MEMORY_SCOPE_AGENT);
            __syncthreads();
            int q = *qslot;
            if (q >= 256) break;
            softmax_row(smem, logit, dout, g * 256 + q, t);
        }
    }
}

// ---------------- persistent recurrence v11 ----------------
// bar: cntA@0, cntB@512, superA@1024, superB@1088, bcastA@1152, bcastB@2688,
//      cntC@4224, qcnt@4288, gd@4352 (6 lines@64), rowq@4736 (6 lines@64)
__global__ __launch_bounds__(512) void recurrence11(
    const float* __restrict__ simxe, const u16* __restrict__ gxe,
    const u16* __restrict__ P, const u16* __restrict__ aw2t,
    const u16* __restrict__ whht, const u16* __restrict__ wiht,
    const float* __restrict__ b_ih, const float* __restrict__ b_hh,
    u16* __restrict__ g_rot, u16* __restrict__ hallx,
    const float* __restrict__ outW, const float* __restrict__ outB,
    u16* __restrict__ outWT, u16* __restrict__ logit, float* __restrict__ dout,
    int* __restrict__ bar, int fused)
{
    __shared__ __align__(16) char smem[155776];
    int* cntA   = bar;
    int* cntB   = bar + 512;
    int* superA = bar + 1024;
    int* superB = bar + 1088;
    int* bcastA = bar + 1152;
    int* bcastB = bar + 2688;
    int* cntC   = bar + 4224;
    int* qcnt   = bar + 4288;
    int* gd     = bar + 4352;
    int* rowq   = bar + 4736;
    int* qslot  = (int*)(smem + 153600);
    const int blk = blockIdx.x, t = threadIdx.x;
    const int lane = t & 63, w = t >> 6;
    const int r16 = lane & 15, kg = lane >> 4;
    const u16* Ab = hallx + NB * NH;

    if (blk < RA_BLOCKS) {
        // =========== ROLE A: sim + softmax-over-batch + g ===========
        int* myB = bcastB + (blk % 24) * 64;
        const int b = blk >> 1, half = blk & 1;
        u16*   W2T  = (u16*)smem;
        u16*   Pl   = (u16*)(smem + 99072);
        float* siml = (float*)(smem + 148224);
        float* wl   = (float*)(smem + 154496);
        u16*   gtmp = (u16*)(smem + 154752);
        for (int idx = t; idx < 48 * 1024; idx += 512) {
            int l = idx >> 10, k = idx & 1023;
            W2T[l * 1032 + k] = aw2t[idx];
        }
        for (int idx = t; idx < 48 * 512; idx += 512) {
            int l = idx >> 9, j = idx & 511;
            Pl[idx] = P[((size_t)(b * 48 + l)) * NH + half * 512 + j];
        }
        __syncthreads();
        const int mt = w & 1, nt = w >> 1;
        const int m0 = mt * 16, n0 = nt * 16;

        for (int s = 0; s < NS; ++s) {
            float gxev = bf2f(gxe[((size_t)(s * 32 + b)) * NH + half * 512 + t]);
            float sxv0 = 0.f, sxv1 = 0.f, sxv2 = 0.f, sxv3 = 0.f;
            if (w < 6) {
                const float* sxe = simxe + (size_t)(s * 32) * NL;
                sxv0 = sxe[(m0 + kg * 4 + 0) * NL + n0 + r16];
                sxv1 = sxe[(m0 + kg * 4 + 1) * NL + n0 + r16];
                sxv2 = sxe[(m0 + kg * 4 + 2) * NL + n0 + r16];
                sxv3 = sxe[(m0 + kg * 4 + 3) * NL + n0 + r16];
            }
            if (t == 0) waitb(myB, s);
            __syncthreads();
            const u16* hprev = hallx + (size_t)s * (NB * NH);
            if (w < 6) {
                f32x4 acc0; f32x4 acc1 = {};
                acc0[0] = sxv0; acc0[1] = sxv1; acc0[2] = sxv2; acc0[3] = sxv3;
                const u16* aP = hprev + (size_t)(m0 + r16) * NH + kg * 8;
                const u16* bP = W2T + (n0 + r16) * 1032 + kg * 8;
#pragma unroll
                for (int k = 0; k < 1024; k += 64) {
                    acc0 = mfma16(*reinterpret_cast<const bf16x8*>(aP + k),
                                  *reinterpret_cast<const bf16x8*>(bP + k), acc0);
                    acc1 = mfma16(*reinterpret_cast<const bf16x8*>(aP + k + 32),
                                  *reinterpret_cast<const bf16x8*>(bP + k + 32), acc1);
                }
#pragma unroll
                for (int rr = 0; rr < 4; ++rr)
                    siml[(m0 + kg * 4 + rr) * 49 + n0 + r16] = acc0[rr] + acc1[rr];
            }
            __syncthreads();
            if (t < 384) {
                int l = t >> 3, p = t & 7;
                float v0 = siml[(p * 4 + 0) * 49 + l];
                float v1 = siml[(p * 4 + 1) * 49 + l];
                float v2 = siml[(p * 4 + 2) * 49 + l];
                float v3 = siml[(p * 4 + 3) * 49 + l];
                float m = fmaxf(fmaxf(v0, v1), fmaxf(v2, v3));
                m = fmaxf(m, __shfl_xor(m, 1));
                m = fmaxf(m, __shfl_xor(m, 2));
                m = fmaxf(m, __shfl_xor(m, 4));
                float den = __expf(v0 - m) + __expf(v1 - m) + __expf(v2 - m) + __expf(v3 - m);
                den += __shfl_xor(den, 1);
                den += __shfl_xor(den, 2);
                den += __shfl_xor(den, 4);
                if (p == (b >> 2)) {
                    int bi = b & 3;
                    float vb = bi == 0 ? v0 : bi == 1 ? v1 : bi == 2 ? v2 : v3;
                    wl[l] = __expf(vb - m) / den;
                }
            }
            __syncthreads();
            {
                float acc = gxev;
#pragma unroll
                for (int l = 0; l < 48; ++l) acc += wl[l] * bf2f(Pl[l * 512 + t]);
                gtmp[t] = f2bf(fmaxf(acc, 0.f));
            }
            __syncthreads();
            if (t < 64) {
                uint4v v = *reinterpret_cast<const uint4v*>(gtmp + t * 8);
                st16_coh(g_rot + (size_t)s * (NB * NH) + (size_t)b * NH + half * 512 + t * 8, v);
            }
            if (t == 0) arrive2(cntA + (blk & 7) * 64, superA, bcastA, 7, s + 1);
        }
        if (fused) {
            if (t == 0) { waitb(myB, 48); waitb(cntC, RC_BLOCKS); }
            __syncthreads();
            queue_gemm(smem, qslot, qcnt, gd + 5 * 64, Ab, outWT, outB, logit, t);
            drain_softmax(smem, qslot, gd, rowq, logit, dout, t);
        }
    } else if (blk < RA_BLOCKS + RB_BLOCKS) {
        // =========== ROLE B: gh, gx, gates, h_new ===========
        const int rb = blk - RA_BLOCKS;
        int* myB = bcastB + (rb % 24) * 64;
        int* myA = bcastA + (rb % 24) * 64;
        const int c0 = rb * 8;
        u16*   Whh = (u16*)smem;
        u16*   Wih = (u16*)(smem + 66048);
        float* ghs = (float*)(smem + 132096);
        float* gxs = (float*)(smem + 140288);
        u16*   htmp = (u16*)(smem + 148480);
        for (int idx = t; idx < 32 * 1024; idx += 512) {
            int pr = idx >> 10, k = idx & 1023;
            u16 vh = 0, vi = 0;
            if (pr < 24) {
                size_t srow = (size_t)((pr >> 3) * 1024 + c0 + (pr & 7));
                vh = whht[srow * NH + k];
                vi = wiht[srow * NH + k];
            }
            Whh[pr * 1032 + k] = vh;
            Wih[pr * 1032 + k] = vi;
        }
        const int gb2 = (t & 255) >> 3, gcol = t & 7;
        const float bxr = b_ih[c0 + gcol], bxz = b_ih[1024 + c0 + gcol], bxn = b_ih[2048 + c0 + gcol];
        const float bhr = b_hh[c0 + gcol], bhz = b_hh[1024 + c0 + gcol], bhn = b_hh[2048 + c0 + gcol];
        __syncthreads();
        const int mt = (w >> 1) & 1, nt = w & 1, kh = w >> 2;
        const int m0 = mt * 16;

        for (int s = 0; s < NS; ++s) {
            if (t == 0) waitb(myB, s);
            __syncthreads();
            const u16* hprev = hallx + (size_t)s * (NB * NH);
            const u16* gcur  = g_rot + (size_t)s * (NB * NH);
            float hold = bf2f(hprev[(size_t)gb2 * NH + c0 + gcol]);
            {
                f32x4 acc0 = {}, acc1 = {};
                const u16* aP = hprev + (size_t)(m0 + r16) * NH + kh * 512 + kg * 8;
                const u16* bP = Whh + (nt * 16 + r16) * 1032 + kh * 512 + kg * 8;
#pragma unroll
                for (int k = 0; k < 512; k += 64) {
                    acc0 = mfma16(*reinterpret_cast<const bf16x8*>(aP + k),
                                  *reinterpret_cast<const bf16x8*>(bP + k), acc0);
                    acc1 = mfma16(*reinterpret_cast<const bf16x8*>(aP + k + 32),
                                  *reinterpret_cast<const bf16x8*>(bP + k + 32), acc1);
                }
#pragma unroll
                for (int rr = 0; rr < 4; ++rr)
                    ghs[kh * 1024 + (m0 + kg * 4 + rr) * 32 + nt * 16 + r16] = acc0[rr] + acc1[rr];
            }
            if (t == 0) waitb(myA, s + 1);
            __syncthreads();
            {
                f32x4 acc0 = {}, acc1 = {};
                const u16* aP = gcur + (size_t)(m0 + r16) * NH + kh * 512 + kg * 8;
                const u16* bP = Wih + (nt * 16 + r16) * 1032 + kh * 512 + kg * 8;
#pragma unroll
                for (int k = 0; k < 512; k += 64) {
                    acc0 = mfma16(*reinterpret_cast<const bf16x8*>(aP + k),
                                  *reinterpret_cast<const bf16x8*>(bP + k), acc0);
                    acc1 = mfma16(*reinterpret_cast<const bf16x8*>(aP + k + 32),
                                  *reinterpret_cast<const bf16x8*>(bP + k + 32), acc1);
                }
#pragma unroll
                for (int rr = 0; rr < 4; ++rr)
                    gxs[kh * 1024 + (m0 + kg * 4 + rr) * 32 + nt * 16 + r16] = acc0[rr] + acc1[rr];
            }
            __syncthreads();
            if (t < 256) {
                float gxr = gxs[gb2 * 32 + gcol]      + gxs[1024 + gb2 * 32 + gcol]      + bxr;
                float gxz = gxs[gb2 * 32 + 8 + gcol]  + gxs[1024 + gb2 * 32 + 8 + gcol]  + bxz;
                float gxn = gxs[gb2 * 32 + 16 + gcol] + gxs[1024 + gb2 * 32 + 16 + gcol] + bxn;
                float ghr = ghs[gb2 * 32 + gcol]      + ghs[1024 + gb2 * 32 + gcol]      + bhr;
                float ghz = ghs[gb2 * 32 + 8 + gcol]  + ghs[1024 + gb2 * 32 + 8 + gcol]  + bhz;
                float ghn = ghs[gb2 * 32 + 16 + gcol] + ghs[1024 + gb2 * 32 + 16 + gcol] + bhn;
                float rg = 1.f / (1.f + __expf(-(gxr + ghr)));
                float zg = 1.f / (1.f + __expf(-(gxz + ghz)));
                float ng = tanhf(gxn + rg * ghn);
                float hnew = (1.f - zg) * ng + zg * hold;
                htmp[t] = f2bf(hnew);
            }
            __syncthreads();
            if (t < 32) {
                uint4v v = *reinterpret_cast<const uint4v*>(htmp + t * 8);
                st16_coh(hallx + ((size_t)(s + 1) * NB + t) * NH + c0, v);
            }
            if (t == 0) arrive2(cntB + (rb & 7) * 64, superB, bcastB, 15, s + 1);
        }
        if (fused) {
            if (t == 0) { waitb(myB, 48); waitb(cntC, RC_BLOCKS); }
            __syncthreads();
            queue_gemm(smem, qslot, qcnt, gd + 5 * 64, Ab, outWT, outB, logit, t);
            drain_softmax(smem, qslot, gd, rowq, logit, dout, t);
        }
    } else {
        // =========== ROLE C: outW transpose, gated 256x256 GEMM groups + fused softmax ======
        const int rc = blk - (RA_BLOCKS + RB_BLOCKS);   // 0..63
        // ---- phase 1: transpose outW -> outWT (coherent)
        {
            float* ttile = (float*)smem;   // [4][32][33] f32
            const int sub = t >> 7, u = t & 127;
            for (int T0 = 0; T0 < 32000; T0 += 256) {
                int T = T0 + rc * 4 + sub;
                int tn = T >> 5, tk = T & 31;
                int n0 = tn * 32, k0 = tk * 32;
                __syncthreads();
#pragma unroll
                for (int j = 0; j < 8; ++j) {
                    int e = j * 128 + u;
                    int row = e >> 5, col = e & 31;
                    ttile[(sub * 32 + row) * 33 + col] = outW[(size_t)(k0 + row) * NV + n0 + col];
                }
                __syncthreads();
                int nr = u >> 2, kc = u & 3;
                unsigned pk0, pk1, pk2, pk3;
                {
                    const float* base = ttile + (sub * 32 + kc * 8) * 33 + nr;
                    pk0 = (unsigned)f2bf(base[0])   | ((unsigned)f2bf(base[33])  << 16);
                    pk1 = (unsigned)f2bf(base[66])  | ((unsigned)f2bf(base[99])  << 16);
                    pk2 = (unsigned)f2bf(base[132]) | ((unsigned)f2bf(base[165]) << 16);
                    pk3 = (unsigned)f2bf(base[198]) | ((unsigned)f2bf(base[231]) << 16);
                }
                uint4v v; v[0] = pk0; v[1] = pk1; v[2] = pk2; v[3] = pk3;
                st16_coh(outWT + (size_t)(n0 + nr) * NH + k0 + kc * 8, v);
            }
            asm volatile("s_waitcnt vmcnt(0)" ::: "memory");
            __syncthreads();
            if (t == 0) {
                __hip_atomic_fetch_add(cntC, 1, __ATOMIC_RELAXED, __HIP_MEMORY_SCOPE_AGENT);
                waitb(cntC, RC_BLOCKS);
            }
            __syncthreads();
        }
        // ---- phase 2: groups 0..4, each gated at 8g+8 steps; then service that group's softmax
        for (int g = 0; g < 5; ++g) {
            if (t == 0) waitb(bcastB + (rc % 24) * 64, 8 * g + 8);
            __syncthreads();
            for (int T = rc; T < 125; T += RC_BLOCKS) {
                do_tile(smem, Ab, outWT, outB, logit, g, T, t);
                if (t == 0) __hip_atomic_fetch_add(gd + g * 64, 1, __ATOMIC_RELAXED, __HIP_MEMORY_SCOPE_AGENT);
            }
            if (t == 0) waitb(gd + g * 64, 125);
            __syncthreads();
            for (;;) {
                __syncthreads();
                if (t == 0) *qslot = __hip_atomic_fetch_add(rowq + g * 64, 1, __ATOMIC_RELAXED, __HIP_MEMORY_SCOPE_AGENT);
                __syncthreads();
                int q = *qslot;
                if (q >= 256) break;
                softmax_row(smem, logit, dout, g * 256 + q, t);
            }
        }
        // ---- phase 3: group 5 queue + final drain
        if (t == 0) waitb(bcastB + (rc % 24) * 64, 48);
        __syncthreads();
        queue_gemm(smem, qslot, qcnt, gd + 5 * 64, Ab, outWT, outB, logit, t);
        drain_softmax(smem, qslot, gd, rowq, logit, dout, t);
    }
}

// ---------------- log_softmax fallback ----------------
__global__ __launch_bounds__(256) void logsoftmax_kernel(float* __restrict__ out) {
    __shared__ float red[8];
    float* row = out + (size_t)blockIdx.x * NV;
    int t = threadIdx.x;
    float m = -1e30f;
    for (int i = t; i < NV; i += 256) m = fmaxf(m, row[i]);
    for (int o = 32; o >= 1; o >>= 1) m = fmaxf(m, __shfl_xor(m, o));
    if ((t & 63) == 0) red[t >> 6] = m;
    __syncthreads();
    m = fmaxf(fmaxf(red[0], red[1]), fmaxf(red[2], red[3]));
    float sum = 0.f;
    for (int i = t; i < NV; i += 256) sum += __expf(row[i] - m);
    for (int o = 32; o >= 1; o >>= 1) sum += __shfl_xor(sum, o);
    if ((t & 63) == 0) red[4 + (t >> 6)] = sum;
    __syncthreads();
    sum = (red[4] + red[5]) + (red[6] + red[7]);
    float lse = m + __logf(sum);
    for (int i = t; i < NV; i += 256) row[i] = row[i] - lse;
}

extern "C" void kernel_launch(void* const* d_in, const int* in_sizes, int n_in,
                              void* d_out, int out_size, void* d_ws, size_t ws_size,
                              hipStream_t stream) {
    const int*   label = (const int*)  d_in[0];
    const float* inith = (const float*)d_in[1];
    const float* enc   = (const float*)d_in[2];
    const float* emb   = (const float*)d_in[3];
    const float* attnW = (const float*)d_in[4];
    const float* attnB = (const float*)d_in[5];
    const float* combW = (const float*)d_in[6];
    const float* combB = (const float*)d_in[7];
    const float* Wih   = (const float*)d_in[8];
    const float* Whh   = (const float*)d_in[9];
    const float* bih   = (const float*)d_in[10];
    const float* bhh   = (const float*)d_in[11];
    const float* outW  = (const float*)d_in[12];
    const float* outB  = (const float*)d_in[13];
    char* ws = (char*)d_ws;

    size_t BAR_OFF    = 0;                                // 32768
    size_t OUTWT_OFF  = 32768;
    size_t WHHT_OFF   = OUTWT_OFF + (size_t)NV*NH*2;
    size_t WIHT_OFF   = WHHT_OFF + (size_t)K3H*NH*2;
    size_t CW1T_OFF   = WIHT_OFF + (size_t)K3H*NH*2;
    size_t CW2T_OFF   = CW1T_OFF + (size_t)NH*NH*2;
    size_t AW2T_OFF   = CW2T_OFF + (size_t)NH*NH*2;
    size_t AW1T_OFF   = AW2T_OFF + (size_t)NL*NH*2;
    size_t XE_OFF     = AW2T_OFF + (size_t)NL*NH*4;
    size_t ENCB_OFF   = XE_OFF   + (size_t)NR*NE*2;
    size_t SIMXE_OFF  = ENCB_OFF + (size_t)NR*NH*2;
    size_t GXE_OFF    = SIMXE_OFF+ (size_t)NR*NL*4;
    size_t P_OFF      = GXE_OFF  + (size_t)NR*NH*2;
    size_t HALL_OFF   = P_OFF    + (size_t)NR*NH*2;
    size_t GROT_OFF   = HALL_OFF + (size_t)(NS+1)*NB*NH*2;
    size_t LOGIT_OFF  = GROT_OFF + (size_t)NS*NB*NH*2;
    size_t TOTAL_NEED = LOGIT_OFF+ (size_t)NR*NV*2;

    int*   bar   = (int*)(ws + BAR_OFF);
    u16*   outWT = (u16*)(ws + OUTWT_OFF);
    u16*   whht  = (u16*)(ws + WHHT_OFF);
    u16*   wiht  = (u16*)(ws + WIHT_OFF);
    u16*   cw1t  = (u16*)(ws + CW1T_OFF);
    u16*   cw2t  = (u16*)(ws + CW2T_OFF);
    u16*   aw2t  = (u16*)(ws + AW2T_OFF);
    u16*   aw1t  = (u16*)(ws + AW1T_OFF);
    u16*   xe    = (u16*)(ws + XE_OFF);
    u16*   encb  = (u16*)(ws + ENCB_OFF);
    float* simxe = (float*)(ws + SIMXE_OFF);
    u16*   gxe   = (u16*)(ws + GXE_OFF);
    u16*   Pb    = (u16*)(ws + P_OFF);
    u16*   hallx = (u16*)(ws + HALL_OFF);
    u16*   grot  = (u16*)(ws + GROT_OFF);
    u16*   logit = (u16*)(ws + LOGIT_OFF);

    hipMemsetAsync(bar, 0, 32768, stream);
    prologue_all<<<3104 + 8320, 256, 0, stream>>>(label, emb, enc, inith, xe, encb, hallx,
                                                  Whh, Wih, combW, attnW,
                                                  whht, wiht, cw1t, cw2t, aw2t, aw1t);

    simxe2_kernel<<<NR, 384, 0, stream>>>(xe, aw1t, attnB, simxe);
    gemm_pro<<<dim3(NR / 128, NH / 128, 2), 256, 0, stream>>>(xe, cw2t, encb, cw1t, gxe, Pb, combB);

    if (ws_size >= TOTAL_NEED) {
        recurrence11<<<NBLK_FULL, 512, 0, stream>>>(simxe, gxe, Pb, aw2t, whht, wiht,
                                                    bih, bhh, grot, hallx,
                                                    outW, outB, outWT, logit, (float*)d_out, bar, 1);
    } else {
        transpose_cast<<<dim3(NV / 32, 32), 256, 0, stream>>>(outW, NH, NV, (char*)outWT, 1);
        recurrence11<<<RA_BLOCKS + RB_BLOCKS, 512, 0, stream>>>(simxe, gxe, Pb, aw2t, whht, wiht,
                                                                bih, bhh, grot, hallx,
                                                                outW, outB, outWT, logit, (float*)d_out, bar, 0);
        gemm_bf16<1><<<dim3(NR / 128, NV / 128), 256, 0, stream>>>(hallx + (size_t)NB * NH, outWT, d_out, outB, NV);
        logsoftmax_kernel<<<NR, 256, 0, stream>>>((float*)d_out);
    }
}

// Round 12
// 956.110 us; speedup vs baseline: 1.0597x; 1.0597x over previous
//
#include <hip/hip_runtime.h>

#define NB 32
#define NS 48
#define NL 48
#define NH 1024
#define NE 1024
#define NV 32000
#define NR (NS*NB)      // 1536
#define K3H 3072
#define RA_BLOCKS 64
#define RB_BLOCKS 128
#define RC_BLOCKS 64
#define NBLK_FULL (RA_BLOCKS + RB_BLOCKS + RC_BLOCKS)   // 256

typedef unsigned short u16;
typedef __bf16 bf16x8 __attribute__((ext_vector_type(8)));
typedef unsigned short ushort8 __attribute__((ext_vector_type(8)));
typedef float f32x4 __attribute__((ext_vector_type(4)));
typedef unsigned int uint4v __attribute__((ext_vector_type(4)));

__device__ __forceinline__ float bf2f(u16 x) {
    union { unsigned u; float f; } c; c.u = ((unsigned)x) << 16; return c.f;
}
__device__ __forceinline__ u16 f2bf(float f) {
    union { float f; unsigned u; } c; c.f = f;
    unsigned r = (c.u + 0x7FFFu + ((c.u >> 16) & 1u)) >> 16;
    return (u16)r;
}
__device__ __forceinline__ f32x4 mfma16(bf16x8 a, bf16x8 b, f32x4 c) {
    return __builtin_amdgcn_mfma_f32_16x16x32_bf16(a, b, c, 0, 0, 0);
}
__device__ __forceinline__ void gld_lds16(const void* g, void* l) {
    __builtin_amdgcn_global_load_lds((const __attribute__((address_space(1))) void*)g,
                                     (__attribute__((address_space(3))) void*)l, 16, 0, 0);
}

// ---- coherent store (write-through, bypass L1/L2), 16B ----
__device__ __forceinline__ void st16_coh(void* p, uint4v v) {
    asm volatile("global_store_dwordx4 %0, %1, off sc0 sc1" :: "v"(p), "v"(v) : "memory");
}
// ---- single-line waiter poll (coherent load) ----
__device__ __forceinline__ void waitb(const int* line, int tgt) {
    if (tgt <= 0) return;
    int guard = 0; int v;
    for (;;) {
        asm volatile("global_load_dword %0, %1, off sc0 sc1\n\ts_waitcnt vmcnt(0)"
                     : "=v"(v) : "v"(line) : "memory");
        if (v >= tgt) return;
        __builtin_amdgcn_s_sleep(1);
        if (++guard > (1 << 20)) return;   // safety valve: wrong answer, not hang
    }
}
// ---- R5-proven producer arrive: cnt line -> super -> broadcast step to 24 lines ----
__device__ __forceinline__ void arrive2(int* cnt, int* superc, int* bcast, int lineMask, int val) {
    asm volatile("s_waitcnt vmcnt(0)" ::: "memory");
    int prev = __hip_atomic_fetch_add(cnt, 1, __ATOMIC_RELAXED, __HIP_MEMORY_SCOPE_AGENT);
    if ((prev & lineMask) == lineMask) {
        int p2 = __hip_atomic_fetch_add(superc, 1, __ATOMIC_RELAXED, __HIP_MEMORY_SCOPE_AGENT);
        if ((p2 & 7) == 7) {
#pragma unroll
            for (int i = 0; i < 24; ++i)
                asm volatile("global_store_dword %0, %1, off sc0 sc1"
                             :: "v"(bcast + i * 64), "v"(val) : "memory");
        }
    }
}

// ---------------- transpose + cast (fallback) ----------------
__global__ __launch_bounds__(256) void transpose_cast(const float* __restrict__ src, int K, int N,
                                                      char* __restrict__ dst, int bf16out) {
    __shared__ float tile[32][33];
    int k0 = blockIdx.y * 32, n0 = blockIdx.x * 32;
    int tx = threadIdx.x & 31, ty = threadIdx.x >> 5;
    for (int i = 0; i < 4; ++i) {
        int n = n0 + tx;
        float v = (n < N) ? src[(size_t)(k0 + ty + i*8) * N + n] : 0.f;
        tile[ty + i*8][tx] = v;
    }
    __syncthreads();
    for (int i = 0; i < 4; ++i) {
        int n = n0 + ty + i*8;
        int k = k0 + tx;
        if (n < N) {
            float v = tile[tx][ty + i*8];
            if (bf16out) ((u16*)dst)[(size_t)n * K + k] = f2bf(v);
            else         ((float*)dst)[(size_t)n * K + k] = v;
        }
    }
}

// ---------------- merged prologue: prep + weight transposes + simxe ----------------
// blocks 0..3103: prep; 3104..11423: transposes; 11424..12959: simxe rows
__global__ __launch_bounds__(256) void prologue_all(
    const int* __restrict__ label, const float* __restrict__ emb,
    const float* __restrict__ enc, const float* __restrict__ inith,
    u16* __restrict__ xe, u16* __restrict__ encb, u16* __restrict__ hallx,
    const float* __restrict__ Whh_, const float* __restrict__ Wih_,
    const float* __restrict__ combW_, const float* __restrict__ attnW_,
    const float* __restrict__ attnB_, float* __restrict__ simxe,
    u16* __restrict__ whht, u16* __restrict__ wiht,
    u16* __restrict__ cw1t, u16* __restrict__ cw2t,
    u16* __restrict__ aw2t, u16* __restrict__ aw1t)
{
    int bid = blockIdx.x, t = threadIdx.x;
    if (bid >= 11424) {
        // ---- simxe[r][l] = relu(emb[label]) . attnW1[:,l] + attnB[l]
        int r = bid - 11424;
        int s = r >> 5, b = r & 31;
        int lab = label[b * NS + s];
        const float* x = emb + (size_t)lab * NE;
        int l = t >> 2, part = t & 3;
        if (l < 48) {
            float acc = 0.f;
            for (int k = part * 256; k < part * 256 + 256; ++k) {
                float v = x[k];
                v = v > 0.f ? v : 0.f;
                acc += v * attnW_[(size_t)k * NL + l];
            }
            acc += __shfl_xor(acc, 1);
            acc += __shfl_xor(acc, 2);
            if (part == 0) simxe[(size_t)r * NL + l] = acc + attnB_[l];
        }
        return;
    }
    if (bid < 3104) {
        int blk = bid;
        if (blk < NR) {
            int s = blk >> 5, b = blk & 31;
            int lab = label[b * NS + s];
            const float* src = emb + (size_t)lab * NE;
            u16* dst = xe + (size_t)blk * NE;
            for (int i = t; i < NE; i += 256) { float v = src[i]; dst[i] = f2bf(v > 0.f ? v : 0.f); }
        } else if (blk < 2 * NR) {
            int r = blk - NR;
            const float* src = enc + (size_t)r * NH;
            u16* dst = encb + (size_t)r * NH;
            for (int i = t; i < NH; i += 256) dst[i] = f2bf(src[i]);
        } else {
            int b = blk - 2 * NR;
            const float* src = inith + (size_t)b * NH;
            u16* dst = hallx + (size_t)b * NH;
            for (int i = t; i < NH; i += 256) dst[i] = f2bf(src[i]);
        }
        return;
    }
    __shared__ float tile[32][33];
    int tb = bid - 3104;
    const float* src; u16* dst; int N, local;
    if (tb < 3072)      { src = Whh_;  dst = whht; N = 3072; local = tb; }
    else if (tb < 6144) { src = Wih_;  dst = wiht; N = 3072; local = tb - 3072; }
    else if (tb < 7168) { src = combW_; dst = cw1t; N = 1024; local = tb - 6144; }
    else if (tb < 8192) { src = combW_ + (size_t)NH * NH; dst = cw2t; N = 1024; local = tb - 7168; }
    else if (tb < 8256) { src = attnW_ + (size_t)NH * NL; dst = aw2t; N = 48; local = tb - 8192; }
    else                { src = attnW_; dst = aw1t; N = 48; local = tb - 8256; }
    int tiles_x = (N + 31) >> 5;
    int n0 = (local % tiles_x) * 32, k0 = (local / tiles_x) * 32;
    int tx = t & 31, ty = t >> 5;
    for (int i = 0; i < 4; ++i) {
        int n = n0 + tx;
        float v = (n < N) ? src[(size_t)(k0 + ty + i*8) * N + n] : 0.f;
        tile[ty + i*8][tx] = v;
    }
    __syncthreads();
    for (int i = 0; i < 4; ++i) {
        int n = n0 + ty + i*8;
        int k = k0 + tx;
        if (n < N) dst[(size_t)n * 1024 + k] = f2bf(tile[tx][ty + i*8]);
    }
}

// ---------------- standalone bf16 MFMA GEMM (fallback) ----------------
template<int MODE>
__global__ __launch_bounds__(256) void gemm_bf16(const u16* __restrict__ A, const u16* __restrict__ Bt,
                                                 void* __restrict__ Cout, const float* __restrict__ bias, int N) {
    __shared__ u16 ldsA[128 * 64];
    __shared__ u16 ldsB[128 * 64];
    const int t = threadIdx.x;
    const int lane = t & 63, w = t >> 6;
    const int wm = w >> 1, wn = w & 1;
    const int m0 = blockIdx.x * 128, n0 = blockIdx.y * 128;
    f32x4 acc[4][4] = {};
    for (int kt = 0; kt < 16; ++kt) {
        const int k0 = kt * 64;
#pragma unroll
        for (int i = 0; i < 4; ++i) {
            int chunk = i * 256 + t;
            int row = chunk >> 3, slot = chunk & 7;
            int srck = ((slot ^ (row & 7)) * 8);
            gld_lds16(A  + (size_t)(m0 + row) * 1024 + k0 + srck, ldsA + (size_t)(i * 256 + w * 64) * 8);
            gld_lds16(Bt + (size_t)(n0 + row) * 1024 + k0 + srck, ldsB + (size_t)(i * 256 + w * 64) * 8);
        }
        asm volatile("s_waitcnt vmcnt(0)" ::: "memory");
        __syncthreads();
#pragma unroll
        for (int kk = 0; kk < 2; ++kk) {
            bf16x8 a[4], b[4];
#pragma unroll
            for (int f = 0; f < 4; ++f) {
                int rowA = wm * 64 + f * 16 + (lane & 15);
                int slotA = (kk * 4 + (lane >> 4)) ^ (rowA & 7);
                a[f] = *reinterpret_cast<const bf16x8*>(ldsA + rowA * 64 + slotA * 8);
                int rowB = wn * 64 + f * 16 + (lane & 15);
                int slotB = (kk * 4 + (lane >> 4)) ^ (rowB & 7);
                b[f] = *reinterpret_cast<const bf16x8*>(ldsB + rowB * 64 + slotB * 8);
            }
#pragma unroll
            for (int fm = 0; fm < 4; ++fm)
#pragma unroll
                for (int fn = 0; fn < 4; ++fn)
                    acc[fm][fn] = mfma16(a[fm], b[fn], acc[fm][fn]);
        }
        __syncthreads();
    }
#pragma unroll
    for (int fm = 0; fm < 4; ++fm) {
#pragma unroll
        for (int fn = 0; fn < 4; ++fn) {
#pragma unroll
            for (int rr = 0; rr < 4; ++rr) {
                int m = m0 + wm * 64 + fm * 16 + (lane >> 4) * 4 + rr;
                int n = n0 + wn * 64 + fn * 16 + (lane & 15);
                float v = acc[fm][fn][rr];
                if (bias) v += bias[n];
                if (MODE == 0)      ((float*)Cout)[(size_t)m * N + n] = v;
                else if (MODE == 2) ((u16*)Cout)[(size_t)m * N + n] = f2bf(v);
                else if (MODE == 1)
                    ((float*)Cout)[((size_t)(m & 31) * NS + (m >> 5)) * NV + n] = v;
                else
                    ((u16*)Cout)[((size_t)(m & 31) * NS + (m >> 5)) * NV + n] = f2bf(v);
            }
        }
    }
}

// ---------------- merged prologue GEMMs (fallback path only) ----------------
__global__ __launch_bounds__(256) void gemm_pro(const u16* __restrict__ xe, const u16* __restrict__ cw2t,
                                                const u16* __restrict__ encb, const u16* __restrict__ cw1t,
                                                u16* __restrict__ gxe, u16* __restrict__ Pb,
                                                const float* __restrict__ combB) {
    __shared__ u16 ldsA[128 * 64];
    __shared__ u16 ldsB[128 * 64];
    const u16 *A, *Bt; u16* C; const float* bias;
    if (blockIdx.z == 0) { A = xe;   Bt = cw2t; C = gxe; bias = combB; }
    else                 { A = encb; Bt = cw1t; C = Pb;  bias = nullptr; }
    const int t = threadIdx.x;
    const int lane = t & 63, w = t >> 6;
    const int wm = w >> 1, wn = w & 1;
    const int m0 = blockIdx.x * 128, n0 = blockIdx.y * 128;
    f32x4 acc[4][4] = {};
    for (int kt = 0; kt < 16; ++kt) {
        const int k0 = kt * 64;
#pragma unroll
        for (int i = 0; i < 4; ++i) {
            int chunk = i * 256 + t;
            int row = chunk >> 3, slot = chunk & 7;
            int srck = ((slot ^ (row & 7)) * 8);
            gld_lds16(A  + (size_t)(m0 + row) * 1024 + k0 + srck, ldsA + (size_t)(i * 256 + w * 64) * 8);
            gld_lds16(Bt + (size_t)(n0 + row) * 1024 + k0 + srck, ldsB + (size_t)(i * 256 + w * 64) * 8);
        }
        asm volatile("s_waitcnt vmcnt(0)" ::: "memory");
        __syncthreads();
#pragma unroll
        for (int kk = 0; kk < 2; ++kk) {
            bf16x8 a[4], b[4];
#pragma unroll
            for (int f = 0; f < 4; ++f) {
                int rowA = wm * 64 + f * 16 + (lane & 15);
                int slotA = (kk * 4 + (lane >> 4)) ^ (rowA & 7);
                a[f] = *reinterpret_cast<const bf16x8*>(ldsA + rowA * 64 + slotA * 8);
                int rowB = wn * 64 + f * 16 + (lane & 15);
                int slotB = (kk * 4 + (lane >> 4)) ^ (rowB & 7);
                b[f] = *reinterpret_cast<const bf16x8*>(ldsB + rowB * 64 + slotB * 8);
            }
#pragma unroll
            for (int fm = 0; fm < 4; ++fm)
#pragma unroll
                for (int fn = 0; fn < 4; ++fn)
                    acc[fm][fn] = mfma16(a[fm], b[fn], acc[fm][fn]);
        }
        __syncthreads();
    }
#pragma unroll
    for (int fm = 0; fm < 4; ++fm) {
#pragma unroll
        for (int fn = 0; fn < 4; ++fn) {
#pragma unroll
            for (int rr = 0; rr < 4; ++rr) {
                int m = m0 + wm * 64 + fm * 16 + (lane >> 4) * 4 + rr;
                int n = n0 + wn * 64 + fn * 16 + (lane & 15);
                float v = acc[fm][fn][rr];
                if (bias) v += bias[n];
                C[(size_t)m * NH + n] = f2bf(v);
            }
        }
    }
}

// ---------------- in-kernel prologue GEMM tile: 128x128, 512 threads, coherent epilogue ----
__device__ __forceinline__ void pre_gemm_tile(char* smem, const u16* A, const u16* Bt,
                                              u16* C, const float* bias, int m0, int n0, int t) {
    u16* ldsA = (u16*)smem;
    u16* ldsB = (u16*)(smem + 16384);
    const int w = t >> 6, lane = t & 63;
    const int r16 = lane & 15, kg = lane >> 4;
    const int wm = w >> 2, wn = w & 3;
    f32x4 acc[4][2] = {};
    for (int kt = 0; kt < 16; ++kt) {
        const int k0 = kt * 64;
#pragma unroll
        for (int i = 0; i < 2; ++i) {
            int chunk = i * 512 + t;
            int row = chunk >> 3, slot = chunk & 7;
            int srck = ((slot ^ (row & 7)) * 8);
            gld_lds16(A  + (size_t)(m0 + row) * 1024 + k0 + srck, ldsA + (size_t)(i * 512 + w * 64) * 8);
            gld_lds16(Bt + (size_t)(n0 + row) * 1024 + k0 + srck, ldsB + (size_t)(i * 512 + w * 64) * 8);
        }
        asm volatile("s_waitcnt vmcnt(0)" ::: "memory");
        __syncthreads();
#pragma unroll
        for (int kk = 0; kk < 2; ++kk) {
            bf16x8 a[4], b[2];
#pragma unroll
            for (int f = 0; f < 4; ++f) {
                int rowA = wm * 64 + f * 16 + r16;
                int slotA = (kk * 4 + kg) ^ (rowA & 7);
                a[f] = *reinterpret_cast<const bf16x8*>(ldsA + rowA * 64 + slotA * 8);
            }
#pragma unroll
            for (int f = 0; f < 2; ++f) {
                int rowB = wn * 32 + f * 16 + r16;
                int slotB = (kk * 4 + kg) ^ (rowB & 7);
                b[f] = *reinterpret_cast<const bf16x8*>(ldsB + rowB * 64 + slotB * 8);
            }
#pragma unroll
            for (int fm = 0; fm < 4; ++fm)
#pragma unroll
                for (int fn = 0; fn < 2; ++fn)
                    acc[fm][fn] = mfma16(a[fm], b[fn], acc[fm][fn]);
        }
        __syncthreads();
    }
    // stage bf16 tile in LDS, then coherent 16B writes (readable cross-XCD within launch)
    u16* stg = (u16*)smem;   // [128][136]
#pragma unroll
    for (int fm = 0; fm < 4; ++fm)
#pragma unroll
        for (int fn = 0; fn < 2; ++fn)
#pragma unroll
            for (int rr = 0; rr < 4; ++rr) {
                int mr = wm * 64 + fm * 16 + kg * 4 + rr;
                int nc = wn * 32 + fn * 16 + r16;
                float v = acc[fm][fn][rr];
                if (bias) v += bias[n0 + nc];
                stg[mr * 136 + nc] = f2bf(v);
            }
    __syncthreads();
#pragma unroll
    for (int i = 0; i < 4; ++i) {
        int vidx = t * 4 + i;             // 0..2047
        int row = vidx >> 4, cv = vidx & 15;
        uint4v v = *reinterpret_cast<const uint4v*>(stg + row * 136 + cv * 8);
        st16_coh(C + (size_t)(m0 + row) * NH + n0 + cv * 8, v);
    }
    __syncthreads();
}

// ---------------- 256x256 out-GEMM tile (R10-proven) ----------------
__device__ __forceinline__ void do_tile(char* smem, const u16* Ab, const u16* outWT,
                                        const float* outB, u16* logit,
                                        int mt, int nt, int t) {
    u16* ldsA = (u16*)smem;             // 256x64 bf16 = 32KB
    u16* ldsB = (u16*)(smem + 32768);   // 256x64 bf16 = 32KB
    const int w = t >> 6, lane = t & 63;
    const int r16 = lane & 15, kg = lane >> 4;
    const int wm = w >> 1, wn = w & 1;
    const int m0 = mt * 256, n0 = nt * 256;
    f32x4 acc[4][8] = {};
    for (int kt = 0; kt < 16; ++kt) {
        const int k0 = kt * 64;
#pragma unroll
        for (int i = 0; i < 4; ++i) {
            int chunk = i * 512 + t;
            int row = chunk >> 3, slot = chunk & 7;
            int srck = ((slot ^ (row & 7)) * 8);
            gld_lds16(Ab + (size_t)(m0 + row) * 1024 + k0 + srck,
                      ldsA + (size_t)(i * 512 + w * 64) * 8);
            gld_lds16(outWT + (size_t)(n0 + row) * 1024 + k0 + srck,
                      ldsB + (size_t)(i * 512 + w * 64) * 8);
        }
        asm volatile("s_waitcnt vmcnt(0)" ::: "memory");
        __syncthreads();
#pragma unroll
        for (int kk = 0; kk < 2; ++kk) {
            bf16x8 a[4], b[8];
#pragma unroll
            for (int f = 0; f < 4; ++f) {
                int rowA = wm * 64 + f * 16 + r16;
                int slotA = (kk * 4 + kg) ^ (rowA & 7);
                a[f] = *reinterpret_cast<const bf16x8*>(ldsA + rowA * 64 + slotA * 8);
            }
#pragma unroll
            for (int f = 0; f < 8; ++f) {
                int rowB = wn * 128 + f * 16 + r16;
                int slotB = (kk * 4 + kg) ^ (rowB & 7);
                b[f] = *reinterpret_cast<const bf16x8*>(ldsB + rowB * 64 + slotB * 8);
            }
#pragma unroll
            for (int fm = 0; fm < 4; ++fm)
#pragma unroll
                for (int fn = 0; fn < 8; ++fn)
                    acc[fm][fn] = mfma16(a[fm], b[fn], acc[fm][fn]);
        }
        __syncthreads();
    }
#pragma unroll
    for (int fm = 0; fm < 4; ++fm) {
#pragma unroll
        for (int fn = 0; fn < 8; ++fn) {
#pragma unroll
            for (int rr = 0; rr < 4; ++rr) {
                int m = m0 + wm * 64 + fm * 16 + kg * 4 + rr;
                int n = n0 + wn * 128 + fn * 16 + r16;
                float v = acc[fm][fn][rr] + outB[n];
                logit[((size_t)(m & 31) * NS + (m >> 5)) * NV + n] = f2bf(v);
            }
        }
    }
}

// queue-driven tail over group mt=5 (125 n-tiles of 256 cols)
__device__ __forceinline__ void queue_gemm(char* smem, int* qslot, int* qcnt,
                                           const u16* Ab, const u16* outWT,
                                           const float* outB, u16* logit, int t) {
    for (;;) {
        __syncthreads();
        if (t == 0) *qslot = __hip_atomic_fetch_add(qcnt, 1, __ATOMIC_RELAXED, __HIP_MEMORY_SCOPE_AGENT);
        __syncthreads();
        int nt = *qslot;
        if (nt >= 125) return;
        do_tile(smem, Ab, outWT, outB, logit, 5, nt, t);
    }
}

// ---------------- persistent recurrence v12 ----------------
// bar: cntA@0, cntB@512, superA@1024, superB@1088, bcastA@1152, bcastB@2688,
//      cntC@4224, qcnt@4288, cntP@4352
__global__ __launch_bounds__(512) void recurrence12(
    const float* __restrict__ simxe, const u16* __restrict__ gxe,
    const u16* __restrict__ P, const u16* __restrict__ aw2t,
    const u16* __restrict__ whht, const u16* __restrict__ wiht,
    const float* __restrict__ b_ih, const float* __restrict__ b_hh,
    u16* __restrict__ g_rot, u16* __restrict__ hallx,
    const float* __restrict__ outW, const float* __restrict__ outB,
    u16* __restrict__ outWT, u16* __restrict__ logit,
    const u16* __restrict__ xe, const u16* __restrict__ encb,
    const u16* __restrict__ cw1t, const u16* __restrict__ cw2t,
    const float* __restrict__ combB,
    u16* __restrict__ gxe_w, u16* __restrict__ Pb_w,
    int* __restrict__ bar, int fused)
{
    __shared__ __align__(16) char smem[155776];
    int* cntA   = bar;
    int* cntB   = bar + 512;
    int* superA = bar + 1024;
    int* superB = bar + 1088;
    int* bcastA = bar + 1152;
    int* bcastB = bar + 2688;
    int* cntC   = bar + 4224;
    int* qcnt   = bar + 4288;
    int* cntP   = bar + 4352;
    int* qslot  = (int*)(smem + 153600);
    const int blk = blockIdx.x, t = threadIdx.x;
    const int lane = t & 63, w = t >> 6;
    const int r16 = lane & 15, kg = lane >> 4;
    const u16* Ab = hallx + NB * NH;

    // ======== pre-phase: prologue GEMMs in-kernel (blocks 0..191, fused only) ========
    if (fused && blk < 192) {
        int z = blk / 96, local = blk % 96;
        int pmt = local >> 3, pnt = local & 7;
        const u16* A  = z ? encb : xe;
        const u16* Bt = z ? cw1t : cw2t;
        u16* C        = z ? Pb_w : gxe_w;
        pre_gemm_tile(smem, A, Bt, C, z ? nullptr : combB, pmt * 128, pnt * 128, t);
        if (t == 0) {
            asm volatile("s_waitcnt vmcnt(0)" ::: "memory");
            __hip_atomic_fetch_add(cntP, 1, __ATOMIC_RELAXED, __HIP_MEMORY_SCOPE_AGENT);
        }
        __syncthreads();
    }

    if (blk < RA_BLOCKS) {
        // =========== ROLE A: sim + softmax-over-batch + g ===========
        if (fused) {
            if (t == 0) waitb(cntP, 192);   // P/gxe ready (coherent, first-read-this-launch)
            __syncthreads();
        }
        int* myB = bcastB + (blk % 24) * 64;
        const int b = blk >> 1, half = blk & 1;
        u16*   W2T  = (u16*)smem;
        u16*   Pl   = (u16*)(smem + 99072);
        float* siml = (float*)(smem + 148224);
        float* wl   = (float*)(smem + 154496);
        u16*   gtmp = (u16*)(smem + 154752);
        for (int idx = t; idx < 48 * 1024; idx += 512) {
            int l = idx >> 10, k = idx & 1023;
            W2T[l * 1032 + k] = aw2t[idx];
        }
        for (int idx = t; idx < 48 * 512; idx += 512) {
            int l = idx >> 9, j = idx & 511;
            Pl[idx] = P[((size_t)(b * 48 + l)) * NH + half * 512 + j];
        }
        __syncthreads();
        const int mt = w & 1, nt = w >> 1;
        const int m0 = mt * 16, n0 = nt * 16;

        for (int s = 0; s < NS; ++s) {
            float gxev = bf2f(gxe[((size_t)(s * 32 + b)) * NH + half * 512 + t]);
            float sxv0 = 0.f, sxv1 = 0.f, sxv2 = 0.f, sxv3 = 0.f;
            if (w < 6) {
                const float* sxe = simxe + (size_t)(s * 32) * NL;
                sxv0 = sxe[(m0 + kg * 4 + 0) * NL + n0 + r16];
                sxv1 = sxe[(m0 + kg * 4 + 1) * NL + n0 + r16];
                sxv2 = sxe[(m0 + kg * 4 + 2) * NL + n0 + r16];
                sxv3 = sxe[(m0 + kg * 4 + 3) * NL + n0 + r16];
            }
            if (t == 0) waitb(myB, s);
            __syncthreads();
            const u16* hprev = hallx + (size_t)s * (NB * NH);
            if (w < 6) {
                f32x4 acc0; f32x4 acc1 = {};
                acc0[0] = sxv0; acc0[1] = sxv1; acc0[2] = sxv2; acc0[3] = sxv3;
                const u16* aP = hprev + (size_t)(m0 + r16) * NH + kg * 8;
                const u16* bP = W2T + (n0 + r16) * 1032 + kg * 8;
#pragma unroll
                for (int k = 0; k < 1024; k += 64) {
                    acc0 = mfma16(*reinterpret_cast<const bf16x8*>(aP + k),
                                  *reinterpret_cast<const bf16x8*>(bP + k), acc0);
                    acc1 = mfma16(*reinterpret_cast<const bf16x8*>(aP + k + 32),
                                  *reinterpret_cast<const bf16x8*>(bP + k + 32), acc1);
                }
#pragma unroll
                for (int rr = 0; rr < 4; ++rr)
                    siml[(m0 + kg * 4 + rr) * 49 + n0 + r16] = acc0[rr] + acc1[rr];
            }
            __syncthreads();
            if (t < 384) {
                int l = t >> 3, p = t & 7;
                float v0 = siml[(p * 4 + 0) * 49 + l];
                float v1 = siml[(p * 4 + 1) * 49 + l];
                float v2 = siml[(p * 4 + 2) * 49 + l];
                float v3 = siml[(p * 4 + 3) * 49 + l];
                float m = fmaxf(fmaxf(v0, v1), fmaxf(v2, v3));
                m = fmaxf(m, __shfl_xor(m, 1));
                m = fmaxf(m, __shfl_xor(m, 2));
                m = fmaxf(m, __shfl_xor(m, 4));
                float den = __expf(v0 - m) + __expf(v1 - m) + __expf(v2 - m) + __expf(v3 - m);
                den += __shfl_xor(den, 1);
                den += __shfl_xor(den, 2);
                den += __shfl_xor(den, 4);
                if (p == (b >> 2)) {
                    int bi = b & 3;
                    float vb = bi == 0 ? v0 : bi == 1 ? v1 : bi == 2 ? v2 : v3;
                    wl[l] = __expf(vb - m) / den;
                }
            }
            __syncthreads();
            {
                float acc = gxev;
#pragma unroll
                for (int l = 0; l < 48; ++l) acc += wl[l] * bf2f(Pl[l * 512 + t]);
                gtmp[t] = f2bf(fmaxf(acc, 0.f));
            }
            __syncthreads();
            if (t < 64) {
                uint4v v = *reinterpret_cast<const uint4v*>(gtmp + t * 8);
                st16_coh(g_rot + (size_t)s * (NB * NH) + (size_t)b * NH + half * 512 + t * 8, v);
            }
            if (t == 0) arrive2(cntA + (blk & 7) * 64, superA, bcastA, 7, s + 1);
        }
        if (fused) {
            if (t == 0) { waitb(myB, 48); waitb(cntC, RC_BLOCKS); }
            __syncthreads();
            queue_gemm(smem, qslot, qcnt, Ab, outWT, outB, logit, t);
        }
    } else if (blk < RA_BLOCKS + RB_BLOCKS) {
        // =========== ROLE B: gh, gx, gates, h_new ===========
        const int rb = blk - RA_BLOCKS;
        int* myB = bcastB + (rb % 24) * 64;
        int* myA = bcastA + (rb % 24) * 64;
        const int c0 = rb * 8;
        u16*   Whh = (u16*)smem;
        u16*   Wih = (u16*)(smem + 66048);
        float* ghs = (float*)(smem + 132096);
        float* gxs = (float*)(smem + 140288);
        u16*   htmp = (u16*)(smem + 148480);
        for (int idx = t; idx < 32 * 1024; idx += 512) {
            int pr = idx >> 10, k = idx & 1023;
            u16 vh = 0, vi = 0;
            if (pr < 24) {
                size_t srow = (size_t)((pr >> 3) * 1024 + c0 + (pr & 7));
                vh = whht[srow * NH + k];
                vi = wiht[srow * NH + k];
            }
            Whh[pr * 1032 + k] = vh;
            Wih[pr * 1032 + k] = vi;
        }
        const int gb2 = (t & 255) >> 3, gcol = t & 7;
        const float bxr = b_ih[c0 + gcol], bxz = b_ih[1024 + c0 + gcol], bxn = b_ih[2048 + c0 + gcol];
        const float bhr = b_hh[c0 + gcol], bhz = b_hh[1024 + c0 + gcol], bhn = b_hh[2048 + c0 + gcol];
        __syncthreads();
        const int mt = (w >> 1) & 1, nt = w & 1, kh = w >> 2;
        const int m0 = mt * 16;

        for (int s = 0; s < NS; ++s) {
            if (t == 0) waitb(myB, s);
            __syncthreads();
            const u16* hprev = hallx + (size_t)s * (NB * NH);
            const u16* gcur  = g_rot + (size_t)s * (NB * NH);
            float hold = bf2f(hprev[(size_t)gb2 * NH + c0 + gcol]);
            {
                f32x4 acc0 = {}, acc1 = {};
                const u16* aP = hprev + (size_t)(m0 + r16) * NH + kh * 512 + kg * 8;
                const u16* bP = Whh + (nt * 16 + r16) * 1032 + kh * 512 + kg * 8;
#pragma unroll
                for (int k = 0; k < 512; k += 64) {
                    acc0 = mfma16(*reinterpret_cast<const bf16x8*>(aP + k),
                                  *reinterpret_cast<const bf16x8*>(bP + k), acc0);
                    acc1 = mfma16(*reinterpret_cast<const bf16x8*>(aP + k + 32),
                                  *reinterpret_cast<const bf16x8*>(bP + k + 32), acc1);
                }
#pragma unroll
                for (int rr = 0; rr < 4; ++rr)
                    ghs[kh * 1024 + (m0 + kg * 4 + rr) * 32 + nt * 16 + r16] = acc0[rr] + acc1[rr];
            }
            if (t == 0) waitb(myA, s + 1);
            __syncthreads();
            {
                f32x4 acc0 = {}, acc1 = {};
                const u16* aP = gcur + (size_t)(m0 + r16) * NH + kh * 512 + kg * 8;
                const u16* bP = Wih + (nt * 16 + r16) * 1032 + kh * 512 + kg * 8;
#pragma unroll
                for (int k = 0; k < 512; k += 64) {
                    acc0 = mfma16(*reinterpret_cast<const bf16x8*>(aP + k),
                                  *reinterpret_cast<const bf16x8*>(bP + k), acc0);
                    acc1 = mfma16(*reinterpret_cast<const bf16x8*>(aP + k + 32),
                                  *reinterpret_cast<const bf16x8*>(bP + k + 32), acc1);
                }
#pragma unroll
                for (int rr = 0; rr < 4; ++rr)
                    gxs[kh * 1024 + (m0 + kg * 4 + rr) * 32 + nt * 16 + r16] = acc0[rr] + acc1[rr];
            }
            __syncthreads();
            if (t < 256) {
                float gxr = gxs[gb2 * 32 + gcol]      + gxs[1024 + gb2 * 32 + gcol]      + bxr;
                float gxz = gxs[gb2 * 32 + 8 + gcol]  + gxs[1024 + gb2 * 32 + 8 + gcol]  + bxz;
                float gxn = gxs[gb2 * 32 + 16 + gcol] + gxs[1024 + gb2 * 32 + 16 + gcol] + bxn;
                float ghr = ghs[gb2 * 32 + gcol]      + ghs[1024 + gb2 * 32 + gcol]      + bhr;
                float ghz = ghs[gb2 * 32 + 8 + gcol]  + ghs[1024 + gb2 * 32 + 8 + gcol]  + bhz;
                float ghn = ghs[gb2 * 32 + 16 + gcol] + ghs[1024 + gb2 * 32 + 16 + gcol] + bhn;
                float rg = 1.f / (1.f + __expf(-(gxr + ghr)));
                float zg = 1.f / (1.f + __expf(-(gxz + ghz)));
                float ng = tanhf(gxn + rg * ghn);
                float hnew = (1.f - zg) * ng + zg * hold;
                htmp[t] = f2bf(hnew);
            }
            __syncthreads();
            if (t < 32) {
                uint4v v = *reinterpret_cast<const uint4v*>(htmp + t * 8);
                st16_coh(hallx + ((size_t)(s + 1) * NB + t) * NH + c0, v);
            }
            if (t == 0) arrive2(cntB + (rb & 7) * 64, superB, bcastB, 15, s + 1);
        }
        if (fused) {
            if (t == 0) { waitb(myB, 48); waitb(cntC, RC_BLOCKS); }
            __syncthreads();
            queue_gemm(smem, qslot, qcnt, Ab, outWT, outB, logit, t);
        }
    } else {
        // =========== ROLE C: outW transpose, then 256x256 out-GEMM ===========
        const int rc = blk - (RA_BLOCKS + RB_BLOCKS);   // 0..63
        {
            float* ttile = (float*)smem;   // [4][32][33] f32
            const int sub = t >> 7, u = t & 127;
            for (int T0 = 0; T0 < 32000; T0 += 256) {
                int T = T0 + rc * 4 + sub;
                int tn = T >> 5, tk = T & 31;
                int n0 = tn * 32, k0 = tk * 32;
                __syncthreads();
#pragma unroll
                for (int j = 0; j < 8; ++j) {
                    int e = j * 128 + u;
                    int row = e >> 5, col = e & 31;
                    ttile[(sub * 32 + row) * 33 + col] = outW[(size_t)(k0 + row) * NV + n0 + col];
                }
                __syncthreads();
                int nr = u >> 2, kc = u & 3;
                unsigned pk0, pk1, pk2, pk3;
                {
                    const float* base = ttile + (sub * 32 + kc * 8) * 33 + nr;
                    pk0 = (unsigned)f2bf(base[0])   | ((unsigned)f2bf(base[33])  << 16);
                    pk1 = (unsigned)f2bf(base[66])  | ((unsigned)f2bf(base[99])  << 16);
                    pk2 = (unsigned)f2bf(base[132]) | ((unsigned)f2bf(base[165]) << 16);
                    pk3 = (unsigned)f2bf(base[198]) | ((unsigned)f2bf(base[231]) << 16);
                }
                uint4v v; v[0] = pk0; v[1] = pk1; v[2] = pk2; v[3] = pk3;
                st16_coh(outWT + (size_t)(n0 + nr) * NH + k0 + kc * 8, v);
            }
            asm volatile("s_waitcnt vmcnt(0)" ::: "memory");
            __syncthreads();
            if (t == 0) {
                __hip_atomic_fetch_add(cntC, 1, __ATOMIC_RELAXED, __HIP_MEMORY_SCOPE_AGENT);
                waitb(cntC, RC_BLOCKS);
            }
            __syncthreads();
        }
        int lastReady = 0;
        for (int T = rc; T < 625; T += RC_BLOCKS) {
            int mt = T / 125, nt = T - mt * 125;
            int need = 8 * mt + 8;
            if (need > lastReady) {
                if (t == 0) waitb(bcastB + (rc % 24) * 64, need);
                lastReady = need;
            }
            __syncthreads();
            do_tile(smem, Ab, outWT, outB, logit, mt, nt, t);
        }
        if (t == 0) waitb(bcastB + (rc % 24) * 64, 48);
        __syncthreads();
        queue_gemm(smem, qslot, qcnt, Ab, outWT, outB, logit, t);
    }
}

// ---------------- log_softmax variants ----------------
__global__ __launch_bounds__(256) void logsoftmax_kernel(float* __restrict__ out) {
    __shared__ float red[8];
    float* row = out + (size_t)blockIdx.x * NV;
    int t = threadIdx.x;
    float m = -1e30f;
    for (int i = t; i < NV; i += 256) m = fmaxf(m, row[i]);
    for (int o = 32; o >= 1; o >>= 1) m = fmaxf(m, __shfl_xor(m, o));
    if ((t & 63) == 0) red[t >> 6] = m;
    __syncthreads();
    m = fmaxf(fmaxf(red[0], red[1]), fmaxf(red[2], red[3]));
    float sum = 0.f;
    for (int i = t; i < NV; i += 256) sum += __expf(row[i] - m);
    for (int o = 32; o >= 1; o >>= 1) sum += __shfl_xor(sum, o);
    if ((t & 63) == 0) red[4 + (t >> 6)] = sum;
    __syncthreads();
    sum = (red[4] + red[5]) + (red[6] + red[7]);
    float lse = m + __logf(sum);
    for (int i = t; i < NV; i += 256) row[i] = row[i] - lse;
}

__global__ __launch_bounds__(1024) void logsoftmax_bf16(const u16* __restrict__ lg, float* __restrict__ out) {
    __shared__ __align__(16) u16 rowb[NV];   // 64000 B
    __shared__ float red[32];
    const u16* src = lg + (size_t)blockIdx.x * NV;
    float* dst = out + (size_t)blockIdx.x * NV;
    int t = threadIdx.x;
    for (int i = t; i < NV / 8; i += 1024)
        ((ushort8*)rowb)[i] = ((const ushort8*)src)[i];
    __syncthreads();
    float m = -1e30f;
    for (int i = t; i < NV; i += 1024) m = fmaxf(m, bf2f(rowb[i]));
    for (int o = 32; o >= 1; o >>= 1) m = fmaxf(m, __shfl_xor(m, o));
    if ((t & 63) == 0) red[t >> 6] = m;
    __syncthreads();
    m = red[0];
#pragma unroll
    for (int i = 1; i < 16; ++i) m = fmaxf(m, red[i]);
    float sum = 0.f;
    for (int i = t; i < NV; i += 1024) sum += __expf(bf2f(rowb[i]) - m);
    for (int o = 32; o >= 1; o >>= 1) sum += __shfl_xor(sum, o);
    if ((t & 63) == 0) red[16 + (t >> 6)] = sum;
    __syncthreads();
    sum = 0.f;
#pragma unroll
    for (int i = 0; i < 16; ++i) sum += red[16 + i];
    float lse = m + __logf(sum);
    for (int i = t; i < NV; i += 1024) dst[i] = bf2f(rowb[i]) - lse;
}

extern "C" void kernel_launch(void* const* d_in, const int* in_sizes, int n_in,
                              void* d_out, int out_size, void* d_ws, size_t ws_size,
                              hipStream_t stream) {
    const int*   label = (const int*)  d_in[0];
    const float* inith = (const float*)d_in[1];
    const float* enc   = (const float*)d_in[2];
    const float* emb   = (const float*)d_in[3];
    const float* attnW = (const float*)d_in[4];
    const float* attnB = (const float*)d_in[5];
    const float* combW = (const float*)d_in[6];
    const float* combB = (const float*)d_in[7];
    const float* Wih   = (const float*)d_in[8];
    const float* Whh   = (const float*)d_in[9];
    const float* bih   = (const float*)d_in[10];
    const float* bhh   = (const float*)d_in[11];
    const float* outW  = (const float*)d_in[12];
    const float* outB  = (const float*)d_in[13];
    char* ws = (char*)d_ws;

    size_t BAR_OFF    = 0;                                // 32768
    size_t OUTWT_OFF  = 32768;
    size_t WHHT_OFF   = OUTWT_OFF + (size_t)NV*NH*2;
    size_t WIHT_OFF   = WHHT_OFF + (size_t)K3H*NH*2;
    size_t CW1T_OFF   = WIHT_OFF + (size_t)K3H*NH*2;
    size_t CW2T_OFF   = CW1T_OFF + (size_t)NH*NH*2;
    size_t AW2T_OFF   = CW2T_OFF + (size_t)NH*NH*2;
    size_t AW1T_OFF   = AW2T_OFF + (size_t)NL*NH*2;
    size_t XE_OFF     = AW2T_OFF + (size_t)NL*NH*4;
    size_t ENCB_OFF   = XE_OFF   + (size_t)NR*NE*2;
    size_t SIMXE_OFF  = ENCB_OFF + (size_t)NR*NH*2;
    size_t GXE_OFF    = SIMXE_OFF+ (size_t)NR*NL*4;
    size_t P_OFF      = GXE_OFF  + (size_t)NR*NH*2;
    size_t HALL_OFF   = P_OFF    + (size_t)NR*NH*2;
    size_t GROT_OFF   = HALL_OFF + (size_t)(NS+1)*NB*NH*2;
    size_t LOGIT_OFF  = GROT_OFF + (size_t)NS*NB*NH*2;
    size_t TOTAL_NEED = LOGIT_OFF+ (size_t)NR*NV*2;

    int*   bar   = (int*)(ws + BAR_OFF);
    u16*   outWT = (u16*)(ws + OUTWT_OFF);
    u16*   whht  = (u16*)(ws + WHHT_OFF);
    u16*   wiht  = (u16*)(ws + WIHT_OFF);
    u16*   cw1t  = (u16*)(ws + CW1T_OFF);
    u16*   cw2t  = (u16*)(ws + CW2T_OFF);
    u16*   aw2t  = (u16*)(ws + AW2T_OFF);
    u16*   aw1t  = (u16*)(ws + AW1T_OFF);
    u16*   xe    = (u16*)(ws + XE_OFF);
    u16*   encb  = (u16*)(ws + ENCB_OFF);
    float* simxe = (float*)(ws + SIMXE_OFF);
    u16*   gxe   = (u16*)(ws + GXE_OFF);
    u16*   Pb    = (u16*)(ws + P_OFF);
    u16*   hallx = (u16*)(ws + HALL_OFF);
    u16*   grot  = (u16*)(ws + GROT_OFF);
    u16*   logit = (u16*)(ws + LOGIT_OFF);

    hipMemsetAsync(bar, 0, 32768, stream);
    prologue_all<<<3104 + 8320 + NR, 256, 0, stream>>>(label, emb, enc, inith, xe, encb, hallx,
                                                       Whh, Wih, combW, attnW, attnB, simxe,
                                                       whht, wiht, cw1t, cw2t, aw2t, aw1t);

    if (ws_size >= TOTAL_NEED) {
        recurrence12<<<NBLK_FULL, 512, 0, stream>>>(simxe, gxe, Pb, aw2t, whht, wiht,
                                                    bih, bhh, grot, hallx,
                                                    outW, outB, outWT, logit,
                                                    xe, encb, cw1t, cw2t, combB, gxe, Pb,
                                                    bar, 1);
        logsoftmax_bf16<<<NR, 1024, 0, stream>>>(logit, (float*)d_out);
    } else {
        gemm_pro<<<dim3(NR / 128, NH / 128, 2), 256, 0, stream>>>(xe, cw2t, encb, cw1t, gxe, Pb, combB);
        transpose_cast<<<dim3(NV / 32, 32), 256, 0, stream>>>(outW, NH, NV, (char*)outWT, 1);
        recurrence12<<<RA_BLOCKS + RB_BLOCKS, 512, 0, stream>>>(simxe, gxe, Pb, aw2t, whht, wiht,
                                                                bih, bhh, grot, hallx,
                                                                outW, outB, outWT, logit,
                                                                xe, encb, cw1t, cw2t, combB, gxe, Pb,
                                                                bar, 0);
        gemm_bf16<1><<<dim3(NR / 128, NV / 128), 256, 0, stream>>>(hallx + (size_t)NB * NH, outWT, d_out, outB, NV);
        logsoftmax_kernel<<<NR, 256, 0, stream>>>((float*)d_out);
    }
}

// Round 13
// 897.766 us; speedup vs baseline: 1.1286x; 1.0650x over previous
//
#include <hip/hip_runtime.h>

#define NB 32
#define NS 48
#define NL 48
#define NH 1024
#define NE 1024
#define NV 32000
#define NR (NS*NB)      // 1536
#define K3H 3072
#define RA_BLOCKS 64
#define RB_BLOCKS 128
#define RC_BLOCKS 64
#define NBLK_FULL (RA_BLOCKS + RB_BLOCKS + RC_BLOCKS)   // 256

typedef unsigned short u16;
typedef __bf16 bf16x8 __attribute__((ext_vector_type(8)));
typedef unsigned short ushort8 __attribute__((ext_vector_type(8)));
typedef float f32x4 __attribute__((ext_vector_type(4)));
typedef unsigned int uint4v __attribute__((ext_vector_type(4)));

__device__ __forceinline__ float bf2f(u16 x) {
    union { unsigned u; float f; } c; c.u = ((unsigned)x) << 16; return c.f;
}
__device__ __forceinline__ u16 f2bf(float f) {
    union { float f; unsigned u; } c; c.f = f;
    unsigned r = (c.u + 0x7FFFu + ((c.u >> 16) & 1u)) >> 16;
    return (u16)r;
}
__device__ __forceinline__ f32x4 mfma16(bf16x8 a, bf16x8 b, f32x4 c) {
    return __builtin_amdgcn_mfma_f32_16x16x32_bf16(a, b, c, 0, 0, 0);
}
__device__ __forceinline__ void gld_lds16(const void* g, void* l) {
    __builtin_amdgcn_global_load_lds((const __attribute__((address_space(1))) void*)g,
                                     (__attribute__((address_space(3))) void*)l, 16, 0, 0);
}

// ---- coherent store (write-through, bypass L1/L2), 16B ----
__device__ __forceinline__ void st16_coh(void* p, uint4v v) {
    asm volatile("global_store_dwordx4 %0, %1, off sc0 sc1" :: "v"(p), "v"(v) : "memory");
}
// ---- single-line waiter poll (coherent load) ----
__device__ __forceinline__ void waitb(const int* line, int tgt) {
    if (tgt <= 0) return;
    int guard = 0; int v;
    for (;;) {
        asm volatile("global_load_dword %0, %1, off sc0 sc1\n\ts_waitcnt vmcnt(0)"
                     : "=v"(v) : "v"(line) : "memory");
        if (v >= tgt) return;
        __builtin_amdgcn_s_sleep(1);
        if (++guard > (1 << 20)) return;   // safety valve: wrong answer, not hang
    }
}
// ---- R5-proven producer arrive: cnt line -> super -> broadcast step to 24 lines ----
__device__ __forceinline__ void arrive2(int* cnt, int* superc, int* bcast, int lineMask, int val) {
    asm volatile("s_waitcnt vmcnt(0)" ::: "memory");   // my coherent data stores are visible
    int prev = __hip_atomic_fetch_add(cnt, 1, __ATOMIC_RELAXED, __HIP_MEMORY_SCOPE_AGENT);
    if ((prev & lineMask) == lineMask) {
        int p2 = __hip_atomic_fetch_add(superc, 1, __ATOMIC_RELAXED, __HIP_MEMORY_SCOPE_AGENT);
        if ((p2 & 7) == 7) {
#pragma unroll
            for (int i = 0; i < 24; ++i)
                asm volatile("global_store_dword %0, %1, off sc0 sc1"
                             :: "v"(bcast + i * 64), "v"(val) : "memory");
        }
    }
}

// ---------------- transpose + cast (single-job fallback) ----------------
__global__ __launch_bounds__(256) void transpose_cast(const float* __restrict__ src, int K, int N,
                                                      char* __restrict__ dst, int bf16out) {
    __shared__ float tile[32][33];
    int k0 = blockIdx.y * 32, n0 = blockIdx.x * 32;
    int tx = threadIdx.x & 31, ty = threadIdx.x >> 5;
    for (int i = 0; i < 4; ++i) {
        int n = n0 + tx;
        float v = (n < N) ? src[(size_t)(k0 + ty + i*8) * N + n] : 0.f;
        tile[ty + i*8][tx] = v;
    }
    __syncthreads();
    for (int i = 0; i < 4; ++i) {
        int n = n0 + ty + i*8;
        int k = k0 + tx;
        if (n < N) {
            float v = tile[tx][ty + i*8];
            if (bf16out) ((u16*)dst)[(size_t)n * K + k] = f2bf(v);
            else         ((float*)dst)[(size_t)n * K + k] = v;
        }
    }
}

// ---------------- merged prologue: prep (blocks 0..3103) + weight transposes ----------------
// (Both parts identical to their R10 standalone forms; no waits, no new sync.)
__global__ __launch_bounds__(256) void prologue_all(
    const int* __restrict__ label, const float* __restrict__ emb,
    const float* __restrict__ enc, const float* __restrict__ inith,
    u16* __restrict__ xe, u16* __restrict__ encb, u16* __restrict__ hallx,
    const float* __restrict__ Whh_, const float* __restrict__ Wih_,
    const float* __restrict__ combW_, const float* __restrict__ attnW_,
    u16* __restrict__ whht, u16* __restrict__ wiht,
    u16* __restrict__ cw1t, u16* __restrict__ cw2t,
    u16* __restrict__ aw2t, u16* __restrict__ aw1t)
{
    int bid = blockIdx.x, t = threadIdx.x;
    if (bid < 3104) {
        int blk = bid;
        if (blk < NR) {
            int s = blk >> 5, b = blk & 31;
            int lab = label[b * NS + s];
            const float* src = emb + (size_t)lab * NE;
            u16* dst = xe + (size_t)blk * NE;
            for (int i = t; i < NE; i += 256) { float v = src[i]; dst[i] = f2bf(v > 0.f ? v : 0.f); }
        } else if (blk < 2 * NR) {
            int r = blk - NR;
            const float* src = enc + (size_t)r * NH;
            u16* dst = encb + (size_t)r * NH;
            for (int i = t; i < NH; i += 256) dst[i] = f2bf(src[i]);
        } else {
            int b = blk - 2 * NR;
            const float* src = inith + (size_t)b * NH;
            u16* dst = hallx + (size_t)b * NH;   // slot 0 = h_{-1}
            for (int i = t; i < NH; i += 256) dst[i] = f2bf(src[i]);
        }
        return;
    }
    __shared__ float tile[32][33];
    int tb = bid - 3104;
    const float* src; u16* dst; int N, local;
    if (tb < 3072)      { src = Whh_;  dst = whht; N = 3072; local = tb; }
    else if (tb < 6144) { src = Wih_;  dst = wiht; N = 3072; local = tb - 3072; }
    else if (tb < 7168) { src = combW_; dst = cw1t; N = 1024; local = tb - 6144; }
    else if (tb < 8192) { src = combW_ + (size_t)NH * NH; dst = cw2t; N = 1024; local = tb - 7168; }
    else if (tb < 8256) { src = attnW_ + (size_t)NH * NL; dst = aw2t; N = 48; local = tb - 8192; }
    else                { src = attnW_; dst = aw1t; N = 48; local = tb - 8256; }
    int tiles_x = (N + 31) >> 5;
    int n0 = (local % tiles_x) * 32, k0 = (local / tiles_x) * 32;
    int tx = t & 31, ty = t >> 5;
    for (int i = 0; i < 4; ++i) {
        int n = n0 + tx;
        float v = (n < N) ? src[(size_t)(k0 + ty + i*8) * N + n] : 0.f;
        tile[ty + i*8][tx] = v;
    }
    __syncthreads();
    for (int i = 0; i < 4; ++i) {
        int n = n0 + ty + i*8;
        int k = k0 + tx;
        if (n < N) dst[(size_t)n * 1024 + k] = f2bf(tile[tx][ty + i*8]);
    }
}

// ---------------- simxe (R10-proven, coalesced via aw1t) ----------------
__global__ __launch_bounds__(384) void simxe2_kernel(const u16* __restrict__ xe, const u16* __restrict__ aw1t,
                                                     const float* __restrict__ attnB, float* __restrict__ simxe) {
    int r = blockIdx.x, t = threadIdx.x;
    int l = t >> 3, part = t & 7;
    const u16* x = xe + (size_t)r * 1024 + part * 128;
    const u16* ww = aw1t + (size_t)l * 1024 + part * 128;
    float acc = 0.f;
#pragma unroll
    for (int k = 0; k < 128; k += 8) {
        ushort8 xv = *reinterpret_cast<const ushort8*>(x + k);
        ushort8 wv = *reinterpret_cast<const ushort8*>(ww + k);
#pragma unroll
        for (int u = 0; u < 8; ++u) acc += bf2f(xv[u]) * bf2f(wv[u]);
    }
    acc += __shfl_xor(acc, 1);
    acc += __shfl_xor(acc, 2);
    acc += __shfl_xor(acc, 4);
    if (part == 0) simxe[(size_t)r * NL + l] = acc + attnB[l];
}

// ---------------- standalone bf16 MFMA GEMM (fallback) ----------------
template<int MODE>
__global__ __launch_bounds__(256) void gemm_bf16(const u16* __restrict__ A, const u16* __restrict__ Bt,
                                                 void* __restrict__ Cout, const float* __restrict__ bias, int N) {
    __shared__ u16 ldsA[128 * 64];
    __shared__ u16 ldsB[128 * 64];
    const int t = threadIdx.x;
    const int lane = t & 63, w = t >> 6;
    const int wm = w >> 1, wn = w & 1;
    const int m0 = blockIdx.x * 128, n0 = blockIdx.y * 128;
    f32x4 acc[4][4] = {};
    for (int kt = 0; kt < 16; ++kt) {
        const int k0 = kt * 64;
#pragma unroll
        for (int i = 0; i < 4; ++i) {
            int chunk = i * 256 + t;
            int row = chunk >> 3, slot = chunk & 7;
            int srck = ((slot ^ (row & 7)) * 8);
            gld_lds16(A  + (size_t)(m0 + row) * 1024 + k0 + srck, ldsA + (size_t)(i * 256 + w * 64) * 8);
            gld_lds16(Bt + (size_t)(n0 + row) * 1024 + k0 + srck, ldsB + (size_t)(i * 256 + w * 64) * 8);
        }
        asm volatile("s_waitcnt vmcnt(0)" ::: "memory");
        __syncthreads();
#pragma unroll
        for (int kk = 0; kk < 2; ++kk) {
            bf16x8 a[4], b[4];
#pragma unroll
            for (int f = 0; f < 4; ++f) {
                int rowA = wm * 64 + f * 16 + (lane & 15);
                int slotA = (kk * 4 + (lane >> 4)) ^ (rowA & 7);
                a[f] = *reinterpret_cast<const bf16x8*>(ldsA + rowA * 64 + slotA * 8);
                int rowB = wn * 64 + f * 16 + (lane & 15);
                int slotB = (kk * 4 + (lane >> 4)) ^ (rowB & 7);
                b[f] = *reinterpret_cast<const bf16x8*>(ldsB + rowB * 64 + slotB * 8);
            }
#pragma unroll
            for (int fm = 0; fm < 4; ++fm)
#pragma unroll
                for (int fn = 0; fn < 4; ++fn)
                    acc[fm][fn] = mfma16(a[fm], b[fn], acc[fm][fn]);
        }
        __syncthreads();
    }
#pragma unroll
    for (int fm = 0; fm < 4; ++fm) {
#pragma unroll
        for (int fn = 0; fn < 4; ++fn) {
#pragma unroll
            for (int rr = 0; rr < 4; ++rr) {
                int m = m0 + wm * 64 + fm * 16 + (lane >> 4) * 4 + rr;
                int n = n0 + wn * 64 + fn * 16 + (lane & 15);
                float v = acc[fm][fn][rr];
                if (bias) v += bias[n];
                if (MODE == 0)      ((float*)Cout)[(size_t)m * N + n] = v;
                else if (MODE == 2) ((u16*)Cout)[(size_t)m * N + n] = f2bf(v);
                else if (MODE == 1)
                    ((float*)Cout)[((size_t)(m & 31) * NS + (m >> 5)) * NV + n] = v;
                else
                    ((u16*)Cout)[((size_t)(m & 31) * NS + (m >> 5)) * NV + n] = f2bf(v);
            }
        }
    }
}

// ---------------- merged prologue GEMMs (gxe and P) in one launch (R10-proven) ------------
__global__ __launch_bounds__(256) void gemm_pro(const u16* __restrict__ xe, const u16* __restrict__ cw2t,
                                                const u16* __restrict__ encb, const u16* __restrict__ cw1t,
                                                u16* __restrict__ gxe, u16* __restrict__ Pb,
                                                const float* __restrict__ combB) {
    __shared__ u16 ldsA[128 * 64];
    __shared__ u16 ldsB[128 * 64];
    const u16 *A, *Bt; u16* C; const float* bias;
    if (blockIdx.z == 0) { A = xe;   Bt = cw2t; C = gxe; bias = combB; }
    else                 { A = encb; Bt = cw1t; C = Pb;  bias = nullptr; }
    const int t = threadIdx.x;
    const int lane = t & 63, w = t >> 6;
    const int wm = w >> 1, wn = w & 1;
    const int m0 = blockIdx.x * 128, n0 = blockIdx.y * 128;
    f32x4 acc[4][4] = {};
    for (int kt = 0; kt < 16; ++kt) {
        const int k0 = kt * 64;
#pragma unroll
        for (int i = 0; i < 4; ++i) {
            int chunk = i * 256 + t;
            int row = chunk >> 3, slot = chunk & 7;
            int srck = ((slot ^ (row & 7)) * 8);
            gld_lds16(A  + (size_t)(m0 + row) * 1024 + k0 + srck, ldsA + (size_t)(i * 256 + w * 64) * 8);
            gld_lds16(Bt + (size_t)(n0 + row) * 1024 + k0 + srck, ldsB + (size_t)(i * 256 + w * 64) * 8);
        }
        asm volatile("s_waitcnt vmcnt(0)" ::: "memory");
        __syncthreads();
#pragma unroll
        for (int kk = 0; kk < 2; ++kk) {
            bf16x8 a[4], b[4];
#pragma unroll
            for (int f = 0; f < 4; ++f) {
                int rowA = wm * 64 + f * 16 + (lane & 15);
                int slotA = (kk * 4 + (lane >> 4)) ^ (rowA & 7);
                a[f] = *reinterpret_cast<const bf16x8*>(ldsA + rowA * 64 + slotA * 8);
                int rowB = wn * 64 + f * 16 + (lane & 15);
                int slotB = (kk * 4 + (lane >> 4)) ^ (rowB & 7);
                b[f] = *reinterpret_cast<const bf16x8*>(ldsB + rowB * 64 + slotB * 8);
            }
#pragma unroll
            for (int fm = 0; fm < 4; ++fm)
#pragma unroll
                for (int fn = 0; fn < 4; ++fn)
                    acc[fm][fn] = mfma16(a[fm], b[fn], acc[fm][fn]);
        }
        __syncthreads();
    }
#pragma unroll
    for (int fm = 0; fm < 4; ++fm) {
#pragma unroll
        for (int fn = 0; fn < 4; ++fn) {
#pragma unroll
            for (int rr = 0; rr < 4; ++rr) {
                int m = m0 + wm * 64 + fm * 16 + (lane >> 4) * 4 + rr;
                int n = n0 + wn * 64 + fn * 16 + (lane & 15);
                float v = acc[fm][fn][rr];
                if (bias) v += bias[n];
                C[(size_t)m * NH + n] = f2bf(v);
            }
        }
    }
}

// ---------------- 256x256 out-GEMM tile (R10-proven) ----------------
__device__ __forceinline__ void do_tile(char* smem, const u16* Ab, const u16* outWT,
                                        const float* outB, u16* logit,
                                        int mt, int nt, int t) {
    u16* ldsA = (u16*)smem;             // 256x64 bf16 = 32KB
    u16* ldsB = (u16*)(smem + 32768);   // 256x64 bf16 = 32KB
    const int w = t >> 6, lane = t & 63;
    const int r16 = lane & 15, kg = lane >> 4;
    const int wm = w >> 1, wn = w & 1;
    const int m0 = mt * 256, n0 = nt * 256;
    f32x4 acc[4][8] = {};
    for (int kt = 0; kt < 16; ++kt) {
        const int k0 = kt * 64;
#pragma unroll
        for (int i = 0; i < 4; ++i) {
            int chunk = i * 512 + t;
            int row = chunk >> 3, slot = chunk & 7;
            int srck = ((slot ^ (row & 7)) * 8);
            gld_lds16(Ab + (size_t)(m0 + row) * 1024 + k0 + srck,
                      ldsA + (size_t)(i * 512 + w * 64) * 8);
            gld_lds16(outWT + (size_t)(n0 + row) * 1024 + k0 + srck,
                      ldsB + (size_t)(i * 512 + w * 64) * 8);
        }
        asm volatile("s_waitcnt vmcnt(0)" ::: "memory");
        __syncthreads();
#pragma unroll
        for (int kk = 0; kk < 2; ++kk) {
            bf16x8 a[4], b[8];
#pragma unroll
            for (int f = 0; f < 4; ++f) {
                int rowA = wm * 64 + f * 16 + r16;
                int slotA = (kk * 4 + kg) ^ (rowA & 7);
                a[f] = *reinterpret_cast<const bf16x8*>(ldsA + rowA * 64 + slotA * 8);
            }
#pragma unroll
            for (int f = 0; f < 8; ++f) {
                int rowB = wn * 128 + f * 16 + r16;
                int slotB = (kk * 4 + kg) ^ (rowB & 7);
                b[f] = *reinterpret_cast<const bf16x8*>(ldsB + rowB * 64 + slotB * 8);
            }
#pragma unroll
            for (int fm = 0; fm < 4; ++fm)
#pragma unroll
                for (int fn = 0; fn < 8; ++fn)
                    acc[fm][fn] = mfma16(a[fm], b[fn], acc[fm][fn]);
        }
        __syncthreads();
    }
#pragma unroll
    for (int fm = 0; fm < 4; ++fm) {
#pragma unroll
        for (int fn = 0; fn < 8; ++fn) {
#pragma unroll
            for (int rr = 0; rr < 4; ++rr) {
                int m = m0 + wm * 64 + fm * 16 + kg * 4 + rr;
                int n = n0 + wn * 128 + fn * 16 + r16;
                float v = acc[fm][fn][rr] + outB[n];
                logit[((size_t)(m & 31) * NS + (m >> 5)) * NV + n] = f2bf(v);
            }
        }
    }
}

// queue-driven tail over group mt=5 (125 n-tiles of 256 cols)
__device__ __forceinline__ void queue_gemm(char* smem, int* qslot, int* qcnt,
                                           const u16* Ab, const u16* outWT,
                                           const float* outB, u16* logit, int t) {
    for (;;) {
        __syncthreads();
        if (t == 0) *qslot = __hip_atomic_fetch_add(qcnt, 1, __ATOMIC_RELAXED, __HIP_MEMORY_SCOPE_AGENT);
        __syncthreads();
        int nt = *qslot;
        if (nt >= 125) return;
        do_tile(smem, Ab, outWT, outB, logit, 5, nt, t);
    }
}

// ---------------- persistent recurrence v13 (body identical to R10's recurrence10) --------
// bar: cntA@0 (8 lines), cntB@512 (8 lines), superA@1024, superB@1088,
//      bcastA@1152 (24 lines@64), bcastB@2688 (24 lines@64), cntC@4224, qcnt@4288
__global__ __launch_bounds__(512) void recurrence13(
    const float* __restrict__ simxe, const u16* __restrict__ gxe,
    const u16* __restrict__ P, const u16* __restrict__ aw2t,
    const u16* __restrict__ whht, const u16* __restrict__ wiht,
    const float* __restrict__ b_ih, const float* __restrict__ b_hh,
    u16* __restrict__ g_rot, u16* __restrict__ hallx,
    const float* __restrict__ outW, const float* __restrict__ outB,
    u16* __restrict__ outWT, u16* __restrict__ logit, int* __restrict__ bar, int fused)
{
    __shared__ __align__(16) char smem[155776];
    int* cntA   = bar;
    int* cntB   = bar + 512;
    int* superA = bar + 1024;
    int* superB = bar + 1088;
    int* bcastA = bar + 1152;
    int* bcastB = bar + 2688;
    int* cntC   = bar + 4224;
    int* qcnt   = bar + 4288;
    int* qslot  = (int*)(smem + 153600);
    const int blk = blockIdx.x, t = threadIdx.x;
    const int lane = t & 63, w = t >> 6;
    const int r16 = lane & 15, kg = lane >> 4;
    const u16* Ab = hallx + NB * NH;

    if (blk < RA_BLOCKS) {
        // =========== ROLE A: sim + softmax-over-batch + g ===========
        int* myB = bcastB + (blk % 24) * 64;
        const int b = blk >> 1, half = blk & 1;
        u16*   W2T  = (u16*)smem;                    // [48][1032] bf16 = 99072
        u16*   Pl   = (u16*)(smem + 99072);          // [48][512] bf16 = 49152
        float* siml = (float*)(smem + 148224);       // [32][49] f32 = 6272
        float* wl   = (float*)(smem + 154496);       // 48 f32
        u16*   gtmp = (u16*)(smem + 154752);         // 512 bf16
        for (int idx = t; idx < 48 * 1024; idx += 512) {
            int l = idx >> 10, k = idx & 1023;
            W2T[l * 1032 + k] = aw2t[idx];
        }
        for (int idx = t; idx < 48 * 512; idx += 512) {
            int l = idx >> 9, j = idx & 511;
            Pl[idx] = P[((size_t)(b * 48 + l)) * NH + half * 512 + j];
        }
        __syncthreads();
        const int mt = w & 1, nt = w >> 1;
        const int m0 = mt * 16, n0 = nt * 16;

        for (int s = 0; s < NS; ++s) {
            float gxev = bf2f(gxe[((size_t)(s * 32 + b)) * NH + half * 512 + t]);
            float sxv0 = 0.f, sxv1 = 0.f, sxv2 = 0.f, sxv3 = 0.f;
            if (w < 6) {
                const float* sxe = simxe + (size_t)(s * 32) * NL;
                sxv0 = sxe[(m0 + kg * 4 + 0) * NL + n0 + r16];
                sxv1 = sxe[(m0 + kg * 4 + 1) * NL + n0 + r16];
                sxv2 = sxe[(m0 + kg * 4 + 2) * NL + n0 + r16];
                sxv3 = sxe[(m0 + kg * 4 + 3) * NL + n0 + r16];
            }
            if (t == 0) waitb(myB, s);
            __syncthreads();
            const u16* hprev = hallx + (size_t)s * (NB * NH);
            if (w < 6) {
                f32x4 acc0; f32x4 acc1 = {};
                acc0[0] = sxv0; acc0[1] = sxv1; acc0[2] = sxv2; acc0[3] = sxv3;
                const u16* aP = hprev + (size_t)(m0 + r16) * NH + kg * 8;
                const u16* bP = W2T + (n0 + r16) * 1032 + kg * 8;
#pragma unroll
                for (int k = 0; k < 1024; k += 64) {
                    acc0 = mfma16(*reinterpret_cast<const bf16x8*>(aP + k),
                                  *reinterpret_cast<const bf16x8*>(bP + k), acc0);
                    acc1 = mfma16(*reinterpret_cast<const bf16x8*>(aP + k + 32),
                                  *reinterpret_cast<const bf16x8*>(bP + k + 32), acc1);
                }
#pragma unroll
                for (int rr = 0; rr < 4; ++rr)
                    siml[(m0 + kg * 4 + rr) * 49 + n0 + r16] = acc0[rr] + acc1[rr];
            }
            __syncthreads();
            if (t < 384) {
                int l = t >> 3, p = t & 7;
                float v0 = siml[(p * 4 + 0) * 49 + l];
                float v1 = siml[(p * 4 + 1) * 49 + l];
                float v2 = siml[(p * 4 + 2) * 49 + l];
                float v3 = siml[(p * 4 + 3) * 49 + l];
                float m = fmaxf(fmaxf(v0, v1), fmaxf(v2, v3));
                m = fmaxf(m, __shfl_xor(m, 1));
                m = fmaxf(m, __shfl_xor(m, 2));
                m = fmaxf(m, __shfl_xor(m, 4));
                float den = __expf(v0 - m) + __expf(v1 - m) + __expf(v2 - m) + __expf(v3 - m);
                den += __shfl_xor(den, 1);
                den += __shfl_xor(den, 2);
                den += __shfl_xor(den, 4);
                if (p == (b >> 2)) {
                    int bi = b & 3;
                    float vb = bi == 0 ? v0 : bi == 1 ? v1 : bi == 2 ? v2 : v3;
                    wl[l] = __expf(vb - m) / den;
                }
            }
            __syncthreads();
            {
                float acc = gxev;
#pragma unroll
                for (int l = 0; l < 48; ++l) acc += wl[l] * bf2f(Pl[l * 512 + t]);
                gtmp[t] = f2bf(fmaxf(acc, 0.f));
            }
            __syncthreads();
            if (t < 64) {
                uint4v v = *reinterpret_cast<const uint4v*>(gtmp + t * 8);
                st16_coh(g_rot + (size_t)s * (NB * NH) + (size_t)b * NH + half * 512 + t * 8, v);
            }
            if (t == 0) arrive2(cntA + (blk & 7) * 64, superA, bcastA, 7, s + 1);
        }
        if (fused) {
            if (t == 0) { waitb(myB, 48); waitb(cntC, RC_BLOCKS); }
            __syncthreads();
            queue_gemm(smem, qslot, qcnt, Ab, outWT, outB, logit, t);
        }
    } else if (blk < RA_BLOCKS + RB_BLOCKS) {
        // =========== ROLE B: gh, gx, gates, h_new ===========
        const int rb = blk - RA_BLOCKS;
        int* myB = bcastB + (rb % 24) * 64;
        int* myA = bcastA + (rb % 24) * 64;
        const int c0 = rb * 8;
        u16*   Whh = (u16*)smem;                     // [32][1032] (rows 24..31 zero)
        u16*   Wih = (u16*)(smem + 66048);
        float* ghs = (float*)(smem + 132096);        // [2][32][32]
        float* gxs = (float*)(smem + 140288);
        u16*   htmp = (u16*)(smem + 148480);         // 256 bf16
        for (int idx = t; idx < 32 * 1024; idx += 512) {
            int pr = idx >> 10, k = idx & 1023;
            u16 vh = 0, vi = 0;
            if (pr < 24) {
                size_t srow = (size_t)((pr >> 3) * 1024 + c0 + (pr & 7));
                vh = whht[srow * NH + k];
                vi = wiht[srow * NH + k];
            }
            Whh[pr * 1032 + k] = vh;
            Wih[pr * 1032 + k] = vi;
        }
        const int gb2 = (t & 255) >> 3, gcol = t & 7;
        const float bxr = b_ih[c0 + gcol], bxz = b_ih[1024 + c0 + gcol], bxn = b_ih[2048 + c0 + gcol];
        const float bhr = b_hh[c0 + gcol], bhz = b_hh[1024 + c0 + gcol], bhn = b_hh[2048 + c0 + gcol];
        __syncthreads();
        const int mt = (w >> 1) & 1, nt = w & 1, kh = w >> 2;
        const int m0 = mt * 16;

        for (int s = 0; s < NS; ++s) {
            if (t == 0) waitb(myB, s);
            __syncthreads();
            const u16* hprev = hallx + (size_t)s * (NB * NH);
            const u16* gcur  = g_rot + (size_t)s * (NB * NH);
            float hold = bf2f(hprev[(size_t)gb2 * NH + c0 + gcol]);
            {
                f32x4 acc0 = {}, acc1 = {};
                const u16* aP = hprev + (size_t)(m0 + r16) * NH + kh * 512 + kg * 8;
                const u16* bP = Whh + (nt * 16 + r16) * 1032 + kh * 512 + kg * 8;
#pragma unroll
                for (int k = 0; k < 512; k += 64) {
                    acc0 = mfma16(*reinterpret_cast<const bf16x8*>(aP + k),
                                  *reinterpret_cast<const bf16x8*>(bP + k), acc0);
                    acc1 = mfma16(*reinterpret_cast<const bf16x8*>(aP + k + 32),
                                  *reinterpret_cast<const bf16x8*>(bP + k + 32), acc1);
                }
#pragma unroll
                for (int rr = 0; rr < 4; ++rr)
                    ghs[kh * 1024 + (m0 + kg * 4 + rr) * 32 + nt * 16 + r16] = acc0[rr] + acc1[rr];
            }
            if (t == 0) waitb(myA, s + 1);
            __syncthreads();
            {
                f32x4 acc0 = {}, acc1 = {};
                const u16* aP = gcur + (size_t)(m0 + r16) * NH + kh * 512 + kg * 8;
                const u16* bP = Wih + (nt * 16 + r16) * 1032 + kh * 512 + kg * 8;
#pragma unroll
                for (int k = 0; k < 512; k += 64) {
                    acc0 = mfma16(*reinterpret_cast<const bf16x8*>(aP + k),
                                  *reinterpret_cast<const bf16x8*>(bP + k), acc0);
                    acc1 = mfma16(*reinterpret_cast<const bf16x8*>(aP + k + 32),
                                  *reinterpret_cast<const bf16x8*>(bP + k + 32), acc1);
                }
#pragma unroll
                for (int rr = 0; rr < 4; ++rr)
                    gxs[kh * 1024 + (m0 + kg * 4 + rr) * 32 + nt * 16 + r16] = acc0[rr] + acc1[rr];
            }
            __syncthreads();
            if (t < 256) {
                float gxr = gxs[gb2 * 32 + gcol]      + gxs[1024 + gb2 * 32 + gcol]      + bxr;
                float gxz = gxs[gb2 * 32 + 8 + gcol]  + gxs[1024 + gb2 * 32 + 8 + gcol]  + bxz;
                float gxn = gxs[gb2 * 32 + 16 + gcol] + gxs[1024 + gb2 * 32 + 16 + gcol] + bxn;
                float ghr = ghs[gb2 * 32 + gcol]      + ghs[1024 + gb2 * 32 + gcol]      + bhr;
                float ghz = ghs[gb2 * 32 + 8 + gcol]  + ghs[1024 + gb2 * 32 + 8 + gcol]  + bhz;
                float ghn = ghs[gb2 * 32 + 16 + gcol] + ghs[1024 + gb2 * 32 + 16 + gcol] + bhn;
                float rg = 1.f / (1.f + __expf(-(gxr + ghr)));
                float zg = 1.f / (1.f + __expf(-(gxz + ghz)));
                float ng = tanhf(gxn + rg * ghn);
                float hnew = (1.f - zg) * ng + zg * hold;
                htmp[t] = f2bf(hnew);
            }
            __syncthreads();
            if (t < 32) {
                uint4v v = *reinterpret_cast<const uint4v*>(htmp + t * 8);
                st16_coh(hallx + ((size_t)(s + 1) * NB + t) * NH + c0, v);
            }
            if (t == 0) arrive2(cntB + (rb & 7) * 64, superB, bcastB, 15, s + 1);
        }
        if (fused) {
            if (t == 0) { waitb(myB, 48); waitb(cntC, RC_BLOCKS); }
            __syncthreads();
            queue_gemm(smem, qslot, qcnt, Ab, outWT, outB, logit, t);
        }
    } else {
        // =========== ROLE C: outW transpose, then 256x256 out-GEMM ===========
        const int rc = blk - (RA_BLOCKS + RB_BLOCKS);   // 0..63
        {
            float* ttile = (float*)smem;   // [4][32][33] f32
            const int sub = t >> 7, u = t & 127;
            for (int T0 = 0; T0 < 32000; T0 += 256) {
                int T = T0 + rc * 4 + sub;
                int tn = T >> 5, tk = T & 31;
                int n0 = tn * 32, k0 = tk * 32;
                __syncthreads();
#pragma unroll
                for (int j = 0; j < 8; ++j) {
                    int e = j * 128 + u;
                    int row = e >> 5, col = e & 31;
                    ttile[(sub * 32 + row) * 33 + col] = outW[(size_t)(k0 + row) * NV + n0 + col];
                }
                __syncthreads();
                int nr = u >> 2, kc = u & 3;
                unsigned pk0, pk1, pk2, pk3;
                {
                    const float* base = ttile + (sub * 32 + kc * 8) * 33 + nr;
                    pk0 = (unsigned)f2bf(base[0])   | ((unsigned)f2bf(base[33])  << 16);
                    pk1 = (unsigned)f2bf(base[66])  | ((unsigned)f2bf(base[99])  << 16);
                    pk2 = (unsigned)f2bf(base[132]) | ((unsigned)f2bf(base[165]) << 16);
                    pk3 = (unsigned)f2bf(base[198]) | ((unsigned)f2bf(base[231]) << 16);
                }
                uint4v v; v[0] = pk0; v[1] = pk1; v[2] = pk2; v[3] = pk3;
                st16_coh(outWT + (size_t)(n0 + nr) * NH + k0 + kc * 8, v);
            }
            asm volatile("s_waitcnt vmcnt(0)" ::: "memory");
            __syncthreads();
            if (t == 0) {
                __hip_atomic_fetch_add(cntC, 1, __ATOMIC_RELAXED, __HIP_MEMORY_SCOPE_AGENT);
                waitb(cntC, RC_BLOCKS);
            }
            __syncthreads();
        }
        int lastReady = 0;
        for (int T = rc; T < 625; T += RC_BLOCKS) {
            int mt = T / 125, nt = T - mt * 125;
            int need = 8 * mt + 8;
            if (need > lastReady) {
                if (t == 0) waitb(bcastB + (rc % 24) * 64, need);
                lastReady = need;
            }
            __syncthreads();
            do_tile(smem, Ab, outWT, outB, logit, mt, nt, t);
        }
        if (t == 0) waitb(bcastB + (rc % 24) * 64, 48);
        __syncthreads();
        queue_gemm(smem, qslot, qcnt, Ab, outWT, outB, logit, t);
    }
}

// ---------------- log_softmax variants ----------------
__global__ __launch_bounds__(256) void logsoftmax_kernel(float* __restrict__ out) {
    __shared__ float red[8];
    float* row = out + (size_t)blockIdx.x * NV;
    int t = threadIdx.x;
    float m = -1e30f;
    for (int i = t; i < NV; i += 256) m = fmaxf(m, row[i]);
    for (int o = 32; o >= 1; o >>= 1) m = fmaxf(m, __shfl_xor(m, o));
    if ((t & 63) == 0) red[t >> 6] = m;
    __syncthreads();
    m = fmaxf(fmaxf(red[0], red[1]), fmaxf(red[2], red[3]));
    float sum = 0.f;
    for (int i = t; i < NV; i += 256) sum += __expf(row[i] - m);
    for (int o = 32; o >= 1; o >>= 1) sum += __shfl_xor(sum, o);
    if ((t & 63) == 0) red[4 + (t >> 6)] = sum;
    __syncthreads();
    sum = (red[4] + red[5]) + (red[6] + red[7]);
    float lse = m + __logf(sum);
    for (int i = t; i < NV; i += 256) row[i] = row[i] - lse;
}

__global__ __launch_bounds__(1024) void logsoftmax_bf16(const u16* __restrict__ lg, float* __restrict__ out) {
    __shared__ __align__(16) u16 rowb[NV];   // 64000 B
    __shared__ float red[32];
    const u16* src = lg + (size_t)blockIdx.x * NV;
    float* dst = out + (size_t)blockIdx.x * NV;
    int t = threadIdx.x;
    for (int i = t; i < NV / 8; i += 1024)
        ((ushort8*)rowb)[i] = ((const ushort8*)src)[i];
    __syncthreads();
    float m = -1e30f;
    for (int i = t; i < NV; i += 1024) m = fmaxf(m, bf2f(rowb[i]));
    for (int o = 32; o >= 1; o >>= 1) m = fmaxf(m, __shfl_xor(m, o));
    if ((t & 63) == 0) red[t >> 6] = m;
    __syncthreads();
    m = red[0];
#pragma unroll
    for (int i = 1; i < 16; ++i) m = fmaxf(m, red[i]);
    float sum = 0.f;
    for (int i = t; i < NV; i += 1024) sum += __expf(bf2f(rowb[i]) - m);
    for (int o = 32; o >= 1; o >>= 1) sum += __shfl_xor(sum, o);
    if ((t & 63) == 0) red[16 + (t >> 6)] = sum;
    __syncthreads();
    sum = 0.f;
#pragma unroll
    for (int i = 0; i < 16; ++i) sum += red[16 + i];
    float lse = m + __logf(sum);
    for (int i = t; i < NV; i += 1024) dst[i] = bf2f(rowb[i]) - lse;
}

extern "C" void kernel_launch(void* const* d_in, const int* in_sizes, int n_in,
                              void* d_out, int out_size, void* d_ws, size_t ws_size,
                              hipStream_t stream) {
    const int*   label = (const int*)  d_in[0];
    const float* inith = (const float*)d_in[1];
    const float* enc   = (const float*)d_in[2];
    const float* emb   = (const float*)d_in[3];
    const float* attnW = (const float*)d_in[4];
    const float* attnB = (const float*)d_in[5];
    const float* combW = (const float*)d_in[6];
    const float* combB = (const float*)d_in[7];
    const float* Wih   = (const float*)d_in[8];
    const float* Whh   = (const float*)d_in[9];
    const float* bih   = (const float*)d_in[10];
    const float* bhh   = (const float*)d_in[11];
    const float* outW  = (const float*)d_in[12];
    const float* outB  = (const float*)d_in[13];
    char* ws = (char*)d_ws;

    size_t BAR_OFF    = 0;                                // 32768 (flag lines)
    size_t OUTWT_OFF  = 32768;
    size_t WHHT_OFF   = OUTWT_OFF + (size_t)NV*NH*2;
    size_t WIHT_OFF   = WHHT_OFF + (size_t)K3H*NH*2;
    size_t CW1T_OFF   = WIHT_OFF + (size_t)K3H*NH*2;
    size_t CW2T_OFF   = CW1T_OFF + (size_t)NH*NH*2;
    size_t AW2T_OFF   = CW2T_OFF + (size_t)NH*NH*2;
    size_t AW1T_OFF   = AW2T_OFF + (size_t)NL*NH*2;
    size_t XE_OFF     = AW2T_OFF + (size_t)NL*NH*4;
    size_t ENCB_OFF   = XE_OFF   + (size_t)NR*NE*2;
    size_t SIMXE_OFF  = ENCB_OFF + (size_t)NR*NH*2;
    size_t GXE_OFF    = SIMXE_OFF+ (size_t)NR*NL*4;
    size_t P_OFF      = GXE_OFF  + (size_t)NR*NH*2;
    size_t HALL_OFF   = P_OFF    + (size_t)NR*NH*2;       // hallx [49][B][H] bf16
    size_t GROT_OFF   = HALL_OFF + (size_t)(NS+1)*NB*NH*2; // g rotated [48][B][H]
    size_t LOGIT_OFF  = GROT_OFF + (size_t)NS*NB*NH*2;    // bf16 logits [NR][NV]
    size_t TOTAL_NEED = LOGIT_OFF+ (size_t)NR*NV*2;

    int*   bar   = (int*)(ws + BAR_OFF);
    u16*   outWT = (u16*)(ws + OUTWT_OFF);
    u16*   whht  = (u16*)(ws + WHHT_OFF);
    u16*   wiht  = (u16*)(ws + WIHT_OFF);
    u16*   cw1t  = (u16*)(ws + CW1T_OFF);
    u16*   cw2t  = (u16*)(ws + CW2T_OFF);
    u16*   aw2t  = (u16*)(ws + AW2T_OFF);
    u16*   aw1t  = (u16*)(ws + AW1T_OFF);
    u16*   xe    = (u16*)(ws + XE_OFF);
    u16*   encb  = (u16*)(ws + ENCB_OFF);
    float* simxe = (float*)(ws + SIMXE_OFF);
    u16*   gxe   = (u16*)(ws + GXE_OFF);
    u16*   Pb    = (u16*)(ws + P_OFF);
    u16*   hallx = (u16*)(ws + HALL_OFF);
    u16*   grot  = (u16*)(ws + GROT_OFF);
    u16*   logit = (u16*)(ws + LOGIT_OFF);

    hipMemsetAsync(bar, 0, 32768, stream);
    prologue_all<<<3104 + 8320, 256, 0, stream>>>(label, emb, enc, inith, xe, encb, hallx,
                                                  Whh, Wih, combW, attnW,
                                                  whht, wiht, cw1t, cw2t, aw2t, aw1t);

    simxe2_kernel<<<NR, 384, 0, stream>>>(xe, aw1t, attnB, simxe);
    gemm_pro<<<dim3(NR / 128, NH / 128, 2), 256, 0, stream>>>(xe, cw2t, encb, cw1t, gxe, Pb, combB);

    if (ws_size >= TOTAL_NEED) {
        recurrence13<<<NBLK_FULL, 512, 0, stream>>>(simxe, gxe, Pb, aw2t, whht, wiht,
                                                    bih, bhh, grot, hallx,
                                                    outW, outB, outWT, logit, bar, 1);
        logsoftmax_bf16<<<NR, 1024, 0, stream>>>(logit, (float*)d_out);
    } else {
        transpose_cast<<<dim3(NV / 32, 32), 256, 0, stream>>>(outW, NH, NV, (char*)outWT, 1);
        recurrence13<<<RA_BLOCKS + RB_BLOCKS, 512, 0, stream>>>(simxe, gxe, Pb, aw2t, whht, wiht,
                                                                bih, bhh, grot, hallx,
                                                                outW, outB, outWT, logit, bar, 0);
        gemm_bf16<1><<<dim3(NR / 128, NV / 128), 256, 0, stream>>>(hallx + (size_t)NB * NH, outWT, d_out, outB, NV);
        logsoftmax_kernel<<<NR, 256, 0, stream>>>((float*)d_out);
    }
}